// Round 1
// baseline (672.295 us; speedup 1.0000x reference)
//
#include <hip/hip_runtime.h>
#include <hip/hip_bf16.h>

#define HID 128
#define NCLS 16
#define NGRAPH 64
#define CHUNK 1024

// ---------------- init: zero accumulators ----------------
__global__ __launch_bounds__(256) void k_init(int* counts, int* cursor,
                                              float* pooled, float* cnt, int n) {
    int i = blockIdx.x * 256 + threadIdx.x;
    if (i < n) { counts[i] = 0; cursor[i] = 0; }
    if (i < NGRAPH * HID) pooled[i] = 0.0f;
    if (i < NGRAPH) cnt[i] = 0.0f;
}

// ---------------- degree histogram over dst ----------------
__global__ __launch_bounds__(256) void k_hist(const int* __restrict__ dst,
                                              int* counts, int e) {
    int i = blockIdx.x * 256 + threadIdx.x;
    if (i < e) atomicAdd(&counts[dst[i]], 1);
}

// ---------------- dinv = rsqrt(deg+1)  (self-loop) ----------------
__global__ __launch_bounds__(256) void k_dinv(const int* __restrict__ counts,
                                              float* dinv, int n) {
    int i = blockIdx.x * 256 + threadIdx.x;
    if (i < n) dinv[i] = rsqrtf((float)(counts[i] + 1));
}

// ---------------- scan step 1: per-chunk sums ----------------
__global__ __launch_bounds__(256) void k_chunksum(const int* __restrict__ counts,
                                                  int* csum, int n) {
    __shared__ int sdata[256];
    int b = blockIdx.x, t = threadIdx.x;
    int base = b * CHUNK + t * 4;
    int s = 0;
    #pragma unroll
    for (int j = 0; j < 4; ++j) { int i = base + j; if (i < n) s += counts[i]; }
    sdata[t] = s; __syncthreads();
    for (int off = 128; off > 0; off >>= 1) {
        if (t < off) sdata[t] += sdata[t + off];
        __syncthreads();
    }
    if (t == 0) csum[b] = sdata[0];
}

// ---------------- scan step 2: serial scan of chunk sums ----------------
__global__ void k_scanchunks(const int* __restrict__ csum, int* coff, int nb) {
    if (blockIdx.x == 0 && threadIdx.x == 0) {
        int run = 0;
        for (int b = 0; b < nb; ++b) { coff[b] = run; run += csum[b]; }
    }
}

// ---------------- scan step 3: per-chunk exclusive scan -> rowptr ----------------
__global__ __launch_bounds__(256) void k_rowptr(const int* __restrict__ counts,
                                                const int* __restrict__ coff,
                                                int* rowptr, int n, int e) {
    __shared__ int sincl[256];
    int b = blockIdx.x, t = threadIdx.x;
    int base = b * CHUNK + t * 4;
    int v[4]; int s = 0;
    #pragma unroll
    for (int j = 0; j < 4; ++j) { int i = base + j; v[j] = (i < n) ? counts[i] : 0; s += v[j]; }
    sincl[t] = s; __syncthreads();
    for (int off = 1; off < 256; off <<= 1) {
        int x = sincl[t];
        int y = (t >= off) ? sincl[t - off] : 0;
        __syncthreads();
        sincl[t] = x + y;
        __syncthreads();
    }
    int run = coff[b] + sincl[t] - s;   // exclusive prefix for this thread's 4 elems
    #pragma unroll
    for (int j = 0; j < 4; ++j) {
        int i = base + j;
        if (i < n) { rowptr[i] = run; run += v[j]; }
    }
    if (b == 0 && t == 0) rowptr[n] = e;
}

// ---------------- CSR fill (scatter edges by dst) ----------------
__global__ __launch_bounds__(256) void k_fill(const int* __restrict__ src,
                                              const int* __restrict__ dst,
                                              const float* __restrict__ dinv,
                                              const int* __restrict__ rowptr,
                                              int* cursor, int* csrc, float* cnorm, int e) {
    int i = blockIdx.x * 256 + threadIdx.x;
    if (i >= e) return;
    int s = src[i], d = dst[i];
    int pos = rowptr[d] + atomicAdd(&cursor[d], 1);
    csrc[pos] = s;
    cnorm[pos] = dinv[s] * dinv[d];
}

// ---------------- GEMM: T[n,128] = (relu?)H[n,128] @ W[128,128] ----------------
// block: 256 threads = 8 rows x 32 col-groups (float4 cols). LDS-stage the 8 rows.
__global__ __launch_bounds__(256) void k_gemm(const float* __restrict__ H,
                                              const float* __restrict__ W,
                                              float* __restrict__ T, int n, int relu_in) {
    __shared__ float4 lds[8][32];
    int t = threadIdx.x;
    int lr = t >> 5;          // 0..7 local row
    int cg = t & 31;          // 0..31 col group (4 cols)
    int r = blockIdx.x * 8 + lr;
    float4 v = make_float4(0.f, 0.f, 0.f, 0.f);
    if (r < n) v = ((const float4*)H)[r * 32 + cg];
    if (relu_in) {
        v.x = fmaxf(v.x, 0.f); v.y = fmaxf(v.y, 0.f);
        v.z = fmaxf(v.z, 0.f); v.w = fmaxf(v.w, 0.f);
    }
    lds[lr][cg] = v;
    __syncthreads();

    float4 acc = make_float4(0.f, 0.f, 0.f, 0.f);
    const float4* W4 = (const float4*)W;
    for (int k = 0; k < HID; k += 4) {
        float4 a = lds[lr][k >> 2];
        float4 w0 = W4[(k + 0) * 32 + cg];
        float4 w1 = W4[(k + 1) * 32 + cg];
        float4 w2 = W4[(k + 2) * 32 + cg];
        float4 w3 = W4[(k + 3) * 32 + cg];
        acc.x = fmaf(a.x, w0.x, acc.x); acc.y = fmaf(a.x, w0.y, acc.y);
        acc.z = fmaf(a.x, w0.z, acc.z); acc.w = fmaf(a.x, w0.w, acc.w);
        acc.x = fmaf(a.y, w1.x, acc.x); acc.y = fmaf(a.y, w1.y, acc.y);
        acc.z = fmaf(a.y, w1.z, acc.z); acc.w = fmaf(a.y, w1.w, acc.w);
        acc.x = fmaf(a.z, w2.x, acc.x); acc.y = fmaf(a.z, w2.y, acc.y);
        acc.z = fmaf(a.z, w2.z, acc.z); acc.w = fmaf(a.z, w2.w, acc.w);
        acc.x = fmaf(a.w, w3.x, acc.x); acc.y = fmaf(a.w, w3.y, acc.y);
        acc.z = fmaf(a.w, w3.z, acc.z); acc.w = fmaf(a.w, w3.w, acc.w);
    }
    if (r < n) ((float4*)T)[r * 32 + cg] = acc;
}

// ---------------- pull aggregation: O[i] = b + T[i]*dinv[i]^2 + sum_nbr T[s]*norm ----------------
// one wave (64 lanes) per node; lane = feature-pair (float2)
__global__ __launch_bounds__(256) void k_agg(const float* __restrict__ T,
                                             float* __restrict__ O,
                                             const int* __restrict__ rowptr,
                                             const int* __restrict__ counts,
                                             const int* __restrict__ csrc,
                                             const float* __restrict__ cnorm,
                                             const float* __restrict__ dinv,
                                             const float* __restrict__ bias, int n) {
    int wid = (blockIdx.x * 256 + threadIdx.x) >> 6;
    int lane = threadIdx.x & 63;
    if (wid >= n) return;
    const float2* T2 = (const float2*)T;
    float di = dinv[wid];
    float2 b2 = ((const float2*)bias)[lane];
    float2 self = T2[wid * 64 + lane];
    float sn = di * di;
    float2 acc;
    acc.x = fmaf(self.x, sn, b2.x);
    acc.y = fmaf(self.y, sn, b2.y);
    int start = rowptr[wid];
    int deg = counts[wid];
    for (int j = 0; j < deg; ++j) {
        int s = csrc[start + j];
        float w = cnorm[start + j];
        float2 v = T2[s * 64 + lane];
        acc.x = fmaf(w, v.x, acc.x);
        acc.y = fmaf(w, v.y, acc.y);
    }
    ((float2*)O)[wid * 64 + lane] = acc;
}

// ---------------- pooling: segment-sum over sorted batch ids ----------------
// one wave per 32-node chunk; lane = feature-pair; run-length flush (batch is sorted)
__global__ __launch_bounds__(256) void k_pool(const float* __restrict__ H,
                                              const int* __restrict__ batch,
                                              float* pooled, float* cnt, int n) {
    int gw = (blockIdx.x * 256 + threadIdx.x) >> 6;
    int lane = threadIdx.x & 63;
    int n0 = gw * 32;
    if (n0 >= n) return;
    int n1 = min(n0 + 32, n);
    const float2* H2 = (const float2*)H;
    int gprev = batch[n0];
    float2 acc = make_float2(0.f, 0.f);
    float runc = 0.f;
    for (int i = n0; i < n1; ++i) {
        int g = batch[i];
        if (g != gprev) {   // wave-uniform branch (batch same across lanes)
            atomicAdd(&pooled[gprev * HID + 2 * lane], acc.x);
            atomicAdd(&pooled[gprev * HID + 2 * lane + 1], acc.y);
            if (lane == 0) atomicAdd(&cnt[gprev], runc);
            acc = make_float2(0.f, 0.f); runc = 0.f; gprev = g;
        }
        float2 v = H2[i * 64 + lane];
        acc.x += v.x; acc.y += v.y; runc += 1.f;
    }
    atomicAdd(&pooled[gprev * HID + 2 * lane], acc.x);
    atomicAdd(&pooled[gprev * HID + 2 * lane + 1], acc.y);
    if (lane == 0) atomicAdd(&cnt[gprev], runc);
}

// ---------------- head: out[g,c] = (pooled[g]/cnt[g]) @ Wc + bc ----------------
__global__ __launch_bounds__(256) void k_head(const float* __restrict__ pooled,
                                              const float* __restrict__ cnt,
                                              const float* __restrict__ Wc,
                                              const float* __restrict__ bc,
                                              float* __restrict__ out) {
    int idx = blockIdx.x * 256 + threadIdx.x;
    if (idx >= NGRAPH * NCLS) return;
    int g = idx >> 4, c = idx & 15;
    float inv = 1.0f / fmaxf(cnt[g], 1.0f);
    float s = 0.f;
    for (int k = 0; k < HID; ++k)
        s = fmaf(pooled[g * HID + k], Wc[k * NCLS + c], s);
    out[idx] = s * inv + bc[c];
}

extern "C" void kernel_launch(void* const* d_in, const int* in_sizes, int n_in,
                              void* d_out, int out_size, void* d_ws, size_t ws_size,
                              hipStream_t stream) {
    const float* x    = (const float*)d_in[0];
    const int*   ei   = (const int*)d_in[1];
    const int*   batch= (const int*)d_in[2];
    const float* W0   = (const float*)d_in[3];
    const float* b0   = (const float*)d_in[4];
    const float* W1   = (const float*)d_in[5];
    const float* b1   = (const float*)d_in[6];
    const float* W2   = (const float*)d_in[7];
    const float* b2   = (const float*)d_in[8];
    const float* Wc   = (const float*)d_in[9];
    const float* bc   = (const float*)d_in[10];
    float* out = (float*)d_out;

    const int N = in_sizes[0] / HID;       // 50000
    const int E = in_sizes[1] / 2;         // 800000
    const int* src = ei;
    const int* dst = ei + E;

    // workspace layout
    char* p = (char*)d_ws;
    auto alloc = [&](size_t bytes) { void* r = (void*)p; p += (bytes + 255) & ~(size_t)255; return r; };
    int*   counts = (int*)alloc((size_t)N * 4);
    int*   cursor = (int*)alloc((size_t)N * 4);
    float* dinv   = (float*)alloc((size_t)N * 4);
    int*   csum   = (int*)alloc(256 * 4);
    int*   coff   = (int*)alloc(256 * 4);
    int*   rowptr = (int*)alloc((size_t)(N + 1) * 4);
    int*   csrc   = (int*)alloc((size_t)E * 4);
    float* cnorm  = (float*)alloc((size_t)E * 4);
    float* pooled = (float*)alloc((size_t)NGRAPH * HID * 4);
    float* cnt    = (float*)alloc((size_t)NGRAPH * 4);
    float* bufA   = (float*)alloc((size_t)N * HID * 4);
    float* bufB   = (float*)alloc((size_t)N * HID * 4);

    const int NB = (N + CHUNK - 1) / CHUNK;

    k_init<<<(N + 255) / 256, 256, 0, stream>>>(counts, cursor, pooled, cnt, N);
    k_hist<<<(E + 255) / 256, 256, 0, stream>>>(dst, counts, E);
    k_dinv<<<(N + 255) / 256, 256, 0, stream>>>(counts, dinv, N);
    k_chunksum<<<NB, 256, 0, stream>>>(counts, csum, N);
    k_scanchunks<<<1, 64, 0, stream>>>(csum, coff, NB);
    k_rowptr<<<NB, 256, 0, stream>>>(counts, coff, rowptr, N, E);
    k_fill<<<(E + 255) / 256, 256, 0, stream>>>(src, dst, dinv, rowptr, cursor, csrc, cnorm, E);

    const int gemm_grid = (N + 7) / 8;
    const int agg_grid  = (N * 64 + 255) / 256;

    // layer 0
    k_gemm<<<gemm_grid, 256, 0, stream>>>(x, W0, bufA, N, 0);
    k_agg<<<agg_grid, 256, 0, stream>>>(bufA, bufB, rowptr, counts, csrc, cnorm, dinv, b0, N);
    // layer 1 (relu applied on GEMM input load)
    k_gemm<<<gemm_grid, 256, 0, stream>>>(bufB, W1, bufA, N, 1);
    k_agg<<<agg_grid, 256, 0, stream>>>(bufA, bufB, rowptr, counts, csrc, cnorm, dinv, b1, N);
    // layer 2
    k_gemm<<<gemm_grid, 256, 0, stream>>>(bufB, W2, bufA, N, 1);
    k_agg<<<agg_grid, 256, 0, stream>>>(bufA, bufB, rowptr, counts, csrc, cnorm, dinv, b2, N);

    // pooling + head
    const int pool_waves = (N + 31) / 32;
    k_pool<<<(pool_waves * 64 + 255) / 256, 256, 0, stream>>>(bufB, batch, pooled, cnt, N);
    k_head<<<(NGRAPH * NCLS + 255) / 256, 256, 0, stream>>>(pooled, cnt, Wc, bc, out);
}

// Round 2
// 419.137 us; speedup vs baseline: 1.6040x; 1.6040x over previous
//
#include <hip/hip_runtime.h>
#include <hip/hip_bf16.h>

#define HID 128
#define NCLS 16
#define NGRAPH 64
#define CHUNK 1024

// ---------------- init: zero accumulators ----------------
__global__ __launch_bounds__(256) void k_init(int* counts, int* cursor,
                                              float* pooled, float* cnt, int n) {
    int i = blockIdx.x * 256 + threadIdx.x;
    if (i < n) { counts[i] = 0; cursor[i] = 0; }
    if (i < NGRAPH * HID) pooled[i] = 0.0f;
    if (i < NGRAPH) cnt[i] = 0.0f;
}

// ---------------- degree histogram over dst ----------------
__global__ __launch_bounds__(256) void k_hist(const int* __restrict__ dst,
                                              int* counts, int e) {
    int i = blockIdx.x * 256 + threadIdx.x;
    if (i < e) atomicAdd(&counts[dst[i]], 1);
}

// ---------------- dinv = rsqrt(deg+1)  (self-loop) ----------------
__global__ __launch_bounds__(256) void k_dinv(const int* __restrict__ counts,
                                              float* dinv, int n) {
    int i = blockIdx.x * 256 + threadIdx.x;
    if (i < n) dinv[i] = rsqrtf((float)(counts[i] + 1));
}

// ---------------- scan step 1: per-chunk sums ----------------
__global__ __launch_bounds__(256) void k_chunksum(const int* __restrict__ counts,
                                                  int* csum, int n) {
    __shared__ int sdata[256];
    int b = blockIdx.x, t = threadIdx.x;
    int base = b * CHUNK + t * 4;
    int s = 0;
    #pragma unroll
    for (int j = 0; j < 4; ++j) { int i = base + j; if (i < n) s += counts[i]; }
    sdata[t] = s; __syncthreads();
    for (int off = 128; off > 0; off >>= 1) {
        if (t < off) sdata[t] += sdata[t + off];
        __syncthreads();
    }
    if (t == 0) csum[b] = sdata[0];
}

// ---------------- scan step 2: serial scan of chunk sums ----------------
__global__ void k_scanchunks(const int* __restrict__ csum, int* coff, int nb) {
    if (blockIdx.x == 0 && threadIdx.x == 0) {
        int run = 0;
        for (int b = 0; b < nb; ++b) { coff[b] = run; run += csum[b]; }
    }
}

// ---------------- scan step 3: per-chunk exclusive scan -> rowptr ----------------
__global__ __launch_bounds__(256) void k_rowptr(const int* __restrict__ counts,
                                                const int* __restrict__ coff,
                                                int* rowptr, int n, int e) {
    __shared__ int sincl[256];
    int b = blockIdx.x, t = threadIdx.x;
    int base = b * CHUNK + t * 4;
    int v[4]; int s = 0;
    #pragma unroll
    for (int j = 0; j < 4; ++j) { int i = base + j; v[j] = (i < n) ? counts[i] : 0; s += v[j]; }
    sincl[t] = s; __syncthreads();
    for (int off = 1; off < 256; off <<= 1) {
        int x = sincl[t];
        int y = (t >= off) ? sincl[t - off] : 0;
        __syncthreads();
        sincl[t] = x + y;
        __syncthreads();
    }
    int run = coff[b] + sincl[t] - s;   // exclusive prefix for this thread's 4 elems
    #pragma unroll
    for (int j = 0; j < 4; ++j) {
        int i = base + j;
        if (i < n) { rowptr[i] = run; run += v[j]; }
    }
    if (b == 0 && t == 0) rowptr[n] = e;
}

// ---------------- CSR fill (scatter edges by dst) ----------------
__global__ __launch_bounds__(256) void k_fill(const int* __restrict__ src,
                                              const int* __restrict__ dst,
                                              const float* __restrict__ dinv,
                                              const int* __restrict__ rowptr,
                                              int* cursor, int* csrc, float* cnorm, int e) {
    int i = blockIdx.x * 256 + threadIdx.x;
    if (i >= e) return;
    int s = src[i], d = dst[i];
    int pos = rowptr[d] + atomicAdd(&cursor[d], 1);
    csrc[pos] = s;
    cnorm[pos] = dinv[s] * dinv[d];
}

// ---------------- GEMM: T[n,128] = (relu?)H[n,128] @ W[128,128] ----------------
// Register-tiled: block = 256 threads = 8 row-groups x 32 col-groups.
// Each thread: 8 rows x 4 cols (float4). Block tile = 64 rows x 128 cols.
// A staged in LDS (32KB); W float4 loads reused across the 8 rows -> W L2
// traffic = 3128 waves x 64KB = 200MB (was 1.6GB).
__global__ __launch_bounds__(256) void k_gemm(const float* __restrict__ H,
                                              const float* __restrict__ W,
                                              float* __restrict__ T, int n, int relu_in) {
    __shared__ float4 lds[64][32];
    int t = threadIdx.x;
    int cg = t & 31;          // col group (float4)
    int rg = t >> 5;          // row group 0..7
    int row0 = blockIdx.x * 64;

    // stage 64 rows; iteration i loads rows rg + i*8 (8 consecutive-ish rows,
    // coalesced: 256 threads cover 8 rows x 32 float4 = 4KB contiguous)
    #pragma unroll
    for (int i = 0; i < 8; ++i) {
        int lr = rg + i * 8;
        int r = row0 + lr;
        float4 v = make_float4(0.f, 0.f, 0.f, 0.f);
        if (r < n) v = ((const float4*)H)[(size_t)r * 32 + cg];
        if (relu_in) {
            v.x = fmaxf(v.x, 0.f); v.y = fmaxf(v.y, 0.f);
            v.z = fmaxf(v.z, 0.f); v.w = fmaxf(v.w, 0.f);
        }
        lds[lr][cg] = v;
    }
    __syncthreads();

    float4 acc[8];
    #pragma unroll
    for (int i = 0; i < 8; ++i) acc[i] = make_float4(0.f, 0.f, 0.f, 0.f);

    const float4* W4 = (const float4*)W;
    #pragma unroll 4
    for (int k = 0; k < HID; k += 4) {
        float4 w0 = W4[(k + 0) * 32 + cg];
        float4 w1 = W4[(k + 1) * 32 + cg];
        float4 w2 = W4[(k + 2) * 32 + cg];
        float4 w3 = W4[(k + 3) * 32 + cg];
        #pragma unroll
        for (int i = 0; i < 8; ++i) {
            float4 a = lds[rg * 8 + i][k >> 2];   // 2-address broadcast (free)
            acc[i].x = fmaf(a.x, w0.x, acc[i].x); acc[i].y = fmaf(a.x, w0.y, acc[i].y);
            acc[i].z = fmaf(a.x, w0.z, acc[i].z); acc[i].w = fmaf(a.x, w0.w, acc[i].w);
            acc[i].x = fmaf(a.y, w1.x, acc[i].x); acc[i].y = fmaf(a.y, w1.y, acc[i].y);
            acc[i].z = fmaf(a.y, w1.z, acc[i].z); acc[i].w = fmaf(a.y, w1.w, acc[i].w);
            acc[i].x = fmaf(a.z, w2.x, acc[i].x); acc[i].y = fmaf(a.z, w2.y, acc[i].y);
            acc[i].z = fmaf(a.z, w2.z, acc[i].z); acc[i].w = fmaf(a.z, w2.w, acc[i].w);
            acc[i].x = fmaf(a.w, w3.x, acc[i].x); acc[i].y = fmaf(a.w, w3.y, acc[i].y);
            acc[i].z = fmaf(a.w, w3.z, acc[i].z); acc[i].w = fmaf(a.w, w3.w, acc[i].w);
        }
    }

    #pragma unroll
    for (int i = 0; i < 8; ++i) {
        int r = row0 + rg * 8 + i;
        if (r < n) ((float4*)T)[(size_t)r * 32 + cg] = acc[i];
    }
}

// ---------------- pull aggregation: O[i] = b + T[i]*dinv[i]^2 + sum_nbr T[s]*norm ----------------
// one wave (64 lanes) per node; lane = feature-pair (float2).
// Edge indices/weights batch-loaded by lanes then shfl-broadcast: removes the
// per-edge dependent index-load -> row-gather latency chain.
__global__ __launch_bounds__(256) void k_agg(const float* __restrict__ T,
                                             float* __restrict__ O,
                                             const int* __restrict__ rowptr,
                                             const int* __restrict__ csrc,
                                             const float* __restrict__ cnorm,
                                             const float* __restrict__ dinv,
                                             const float* __restrict__ bias, int n) {
    int wid = (blockIdx.x * 256 + threadIdx.x) >> 6;
    int lane = threadIdx.x & 63;
    if (wid >= n) return;
    const float2* T2 = (const float2*)T;
    float di = dinv[wid];
    float2 b2 = ((const float2*)bias)[lane];
    float2 self = T2[(size_t)wid * 64 + lane];
    float sn = di * di;
    float2 acc;
    acc.x = fmaf(self.x, sn, b2.x);
    acc.y = fmaf(self.y, sn, b2.y);
    int start = rowptr[wid];
    int deg = rowptr[wid + 1] - start;
    for (int j0 = 0; j0 < deg; j0 += 64) {
        int myj = j0 + lane;
        int s = 0; float w = 0.f;
        if (myj < deg) { s = csrc[start + myj]; w = cnorm[start + myj]; }
        int m = min(64, deg - j0);
        for (int jj = 0; jj < m; ++jj) {
            int sj = __shfl(s, jj);
            float wj = __shfl(w, jj);
            float2 v = T2[(size_t)sj * 64 + lane];
            acc.x = fmaf(wj, v.x, acc.x);
            acc.y = fmaf(wj, v.y, acc.y);
        }
    }
    ((float2*)O)[(size_t)wid * 64 + lane] = acc;
}

// ---------------- pooling: segment-sum over sorted batch ids ----------------
__global__ __launch_bounds__(256) void k_pool(const float* __restrict__ H,
                                              const int* __restrict__ batch,
                                              float* pooled, float* cnt, int n) {
    int gw = (blockIdx.x * 256 + threadIdx.x) >> 6;
    int lane = threadIdx.x & 63;
    int n0 = gw * 32;
    if (n0 >= n) return;
    int n1 = min(n0 + 32, n);
    const float2* H2 = (const float2*)H;
    int gprev = batch[n0];
    float2 acc = make_float2(0.f, 0.f);
    float runc = 0.f;
    for (int i = n0; i < n1; ++i) {
        int g = batch[i];
        if (g != gprev) {   // wave-uniform branch (batch same across lanes)
            atomicAdd(&pooled[gprev * HID + 2 * lane], acc.x);
            atomicAdd(&pooled[gprev * HID + 2 * lane + 1], acc.y);
            if (lane == 0) atomicAdd(&cnt[gprev], runc);
            acc = make_float2(0.f, 0.f); runc = 0.f; gprev = g;
        }
        float2 v = H2[(size_t)i * 64 + lane];
        acc.x += v.x; acc.y += v.y; runc += 1.f;
    }
    atomicAdd(&pooled[gprev * HID + 2 * lane], acc.x);
    atomicAdd(&pooled[gprev * HID + 2 * lane + 1], acc.y);
    if (lane == 0) atomicAdd(&cnt[gprev], runc);
}

// ---------------- head: out[g,c] = (pooled[g]/cnt[g]) @ Wc + bc ----------------
__global__ __launch_bounds__(256) void k_head(const float* __restrict__ pooled,
                                              const float* __restrict__ cnt,
                                              const float* __restrict__ Wc,
                                              const float* __restrict__ bc,
                                              float* __restrict__ out) {
    int idx = blockIdx.x * 256 + threadIdx.x;
    if (idx >= NGRAPH * NCLS) return;
    int g = idx >> 4, c = idx & 15;
    float inv = 1.0f / fmaxf(cnt[g], 1.0f);
    float s = 0.f;
    for (int k = 0; k < HID; ++k)
        s = fmaf(pooled[g * HID + k], Wc[k * NCLS + c], s);
    out[idx] = s * inv + bc[c];
}

extern "C" void kernel_launch(void* const* d_in, const int* in_sizes, int n_in,
                              void* d_out, int out_size, void* d_ws, size_t ws_size,
                              hipStream_t stream) {
    const float* x    = (const float*)d_in[0];
    const int*   ei   = (const int*)d_in[1];
    const int*   batch= (const int*)d_in[2];
    const float* W0   = (const float*)d_in[3];
    const float* b0   = (const float*)d_in[4];
    const float* W1   = (const float*)d_in[5];
    const float* b1   = (const float*)d_in[6];
    const float* W2   = (const float*)d_in[7];
    const float* b2   = (const float*)d_in[8];
    const float* Wc   = (const float*)d_in[9];
    const float* bc   = (const float*)d_in[10];
    float* out = (float*)d_out;

    const int N = in_sizes[0] / HID;       // 50000
    const int E = in_sizes[1] / 2;         // 800000
    const int* src = ei;
    const int* dst = ei + E;

    // workspace layout
    char* p = (char*)d_ws;
    auto alloc = [&](size_t bytes) { void* r = (void*)p; p += (bytes + 255) & ~(size_t)255; return r; };
    int*   counts = (int*)alloc((size_t)N * 4);
    int*   cursor = (int*)alloc((size_t)N * 4);
    float* dinv   = (float*)alloc((size_t)N * 4);
    int*   csum   = (int*)alloc(256 * 4);
    int*   coff   = (int*)alloc(256 * 4);
    int*   rowptr = (int*)alloc((size_t)(N + 1) * 4);
    int*   csrc   = (int*)alloc((size_t)E * 4);
    float* cnorm  = (float*)alloc((size_t)E * 4);
    float* pooled = (float*)alloc((size_t)NGRAPH * HID * 4);
    float* cnt    = (float*)alloc((size_t)NGRAPH * 4);
    float* bufA   = (float*)alloc((size_t)N * HID * 4);
    float* bufB   = (float*)alloc((size_t)N * HID * 4);

    const int NB = (N + CHUNK - 1) / CHUNK;

    k_init<<<(N + 255) / 256, 256, 0, stream>>>(counts, cursor, pooled, cnt, N);
    k_hist<<<(E + 255) / 256, 256, 0, stream>>>(dst, counts, E);
    k_dinv<<<(N + 255) / 256, 256, 0, stream>>>(counts, dinv, N);
    k_chunksum<<<NB, 256, 0, stream>>>(counts, csum, N);
    k_scanchunks<<<1, 64, 0, stream>>>(csum, coff, NB);
    k_rowptr<<<NB, 256, 0, stream>>>(counts, coff, rowptr, N, E);
    k_fill<<<(E + 255) / 256, 256, 0, stream>>>(src, dst, dinv, rowptr, cursor, csrc, cnorm, E);

    const int gemm_grid = (N + 63) / 64;
    const int agg_grid  = ((size_t)N * 64 + 255) / 256;

    // layer 0
    k_gemm<<<gemm_grid, 256, 0, stream>>>(x, W0, bufA, N, 0);
    k_agg<<<agg_grid, 256, 0, stream>>>(bufA, bufB, rowptr, csrc, cnorm, dinv, b0, N);
    // layer 1 (relu applied on GEMM input load)
    k_gemm<<<gemm_grid, 256, 0, stream>>>(bufB, W1, bufA, N, 1);
    k_agg<<<agg_grid, 256, 0, stream>>>(bufA, bufB, rowptr, csrc, cnorm, dinv, b1, N);
    // layer 2
    k_gemm<<<gemm_grid, 256, 0, stream>>>(bufB, W2, bufA, N, 1);
    k_agg<<<agg_grid, 256, 0, stream>>>(bufA, bufB, rowptr, csrc, cnorm, dinv, b2, N);

    // pooling + head
    const int pool_waves = (N + 31) / 32;
    k_pool<<<(pool_waves * 64 + 255) / 256, 256, 0, stream>>>(bufB, batch, pooled, cnt, N);
    k_head<<<(NGRAPH * NCLS + 255) / 256, 256, 0, stream>>>(pooled, cnt, Wc, bc, out);
}

// Round 3
// 397.174 us; speedup vs baseline: 1.6927x; 1.0553x over previous
//
#include <hip/hip_runtime.h>
#include <hip/hip_bf16.h>

#define HID 128
#define NCLS 16
#define NGRAPH 64
#define CHUNK 1024

// ---------------- init: zero accumulators ----------------
__global__ __launch_bounds__(256) void k_init(int* counts, int* cursor,
                                              float* pooled, float* cnt, int n) {
    int i = blockIdx.x * 256 + threadIdx.x;
    if (i < n) { counts[i] = 0; cursor[i] = 0; }
    if (i < NGRAPH * HID) pooled[i] = 0.0f;
    if (i < NGRAPH) cnt[i] = 0.0f;
}

// ---------------- degree histogram over dst ----------------
__global__ __launch_bounds__(256) void k_hist(const int* __restrict__ dst,
                                              int* counts, int e) {
    int i = blockIdx.x * 256 + threadIdx.x;
    if (i < e) atomicAdd(&counts[dst[i]], 1);
}

// ---------------- dinv = rsqrt(deg+1)  (self-loop) ----------------
__global__ __launch_bounds__(256) void k_dinv(const int* __restrict__ counts,
                                              float* dinv, int n) {
    int i = blockIdx.x * 256 + threadIdx.x;
    if (i < n) dinv[i] = rsqrtf((float)(counts[i] + 1));
}

// ---------------- scan step 1: per-chunk sums ----------------
__global__ __launch_bounds__(256) void k_chunksum(const int* __restrict__ counts,
                                                  int* csum, int n) {
    __shared__ int sdata[256];
    int b = blockIdx.x, t = threadIdx.x;
    int base = b * CHUNK + t * 4;
    int s = 0;
    #pragma unroll
    for (int j = 0; j < 4; ++j) { int i = base + j; if (i < n) s += counts[i]; }
    sdata[t] = s; __syncthreads();
    for (int off = 128; off > 0; off >>= 1) {
        if (t < off) sdata[t] += sdata[t + off];
        __syncthreads();
    }
    if (t == 0) csum[b] = sdata[0];
}

// ---------------- scan step 2: serial scan of chunk sums ----------------
__global__ void k_scanchunks(const int* __restrict__ csum, int* coff, int nb) {
    if (blockIdx.x == 0 && threadIdx.x == 0) {
        int run = 0;
        for (int b = 0; b < nb; ++b) { coff[b] = run; run += csum[b]; }
    }
}

// ---------------- scan step 3: per-chunk exclusive scan -> rowptr ----------------
__global__ __launch_bounds__(256) void k_rowptr(const int* __restrict__ counts,
                                                const int* __restrict__ coff,
                                                int* rowptr, int n, int e) {
    __shared__ int sincl[256];
    int b = blockIdx.x, t = threadIdx.x;
    int base = b * CHUNK + t * 4;
    int v[4]; int s = 0;
    #pragma unroll
    for (int j = 0; j < 4; ++j) { int i = base + j; v[j] = (i < n) ? counts[i] : 0; s += v[j]; }
    sincl[t] = s; __syncthreads();
    for (int off = 1; off < 256; off <<= 1) {
        int x = sincl[t];
        int y = (t >= off) ? sincl[t - off] : 0;
        __syncthreads();
        sincl[t] = x + y;
        __syncthreads();
    }
    int run = coff[b] + sincl[t] - s;   // exclusive prefix for this thread's 4 elems
    #pragma unroll
    for (int j = 0; j < 4; ++j) {
        int i = base + j;
        if (i < n) { rowptr[i] = run; run += v[j]; }
    }
    if (b == 0 && t == 0) rowptr[n] = e;
}

// ---------------- CSR fill (scatter edges by dst) ----------------
__global__ __launch_bounds__(256) void k_fill(const int* __restrict__ src,
                                              const int* __restrict__ dst,
                                              const float* __restrict__ dinv,
                                              const int* __restrict__ rowptr,
                                              int* cursor, int* csrc, float* cnorm, int e) {
    int i = blockIdx.x * 256 + threadIdx.x;
    if (i >= e) return;
    int s = src[i], d = dst[i];
    int pos = rowptr[d] + atomicAdd(&cursor[d], 1);
    csrc[pos] = s;
    cnorm[pos] = dinv[s] * dinv[d];
}

// ---------------- GEMM: T[n,128] = (relu?)H[n,128] @ W[128,128] ----------------
// Register-tiled: block = 256 threads = 8 row-groups x 32 col-groups.
// Each thread: 8 rows x 4 cols (float4). Block tile = 64 rows x 128 cols.
__global__ __launch_bounds__(256) void k_gemm(const float* __restrict__ H,
                                              const float* __restrict__ W,
                                              float* __restrict__ T, int n, int relu_in) {
    __shared__ float4 lds[64][32];
    int t = threadIdx.x;
    int cg = t & 31;          // col group (float4)
    int rg = t >> 5;          // row group 0..7
    int row0 = blockIdx.x * 64;

    #pragma unroll
    for (int i = 0; i < 8; ++i) {
        int lr = rg + i * 8;
        int r = row0 + lr;
        float4 v = make_float4(0.f, 0.f, 0.f, 0.f);
        if (r < n) v = ((const float4*)H)[(size_t)r * 32 + cg];
        if (relu_in) {
            v.x = fmaxf(v.x, 0.f); v.y = fmaxf(v.y, 0.f);
            v.z = fmaxf(v.z, 0.f); v.w = fmaxf(v.w, 0.f);
        }
        lds[lr][cg] = v;
    }
    __syncthreads();

    float4 acc[8];
    #pragma unroll
    for (int i = 0; i < 8; ++i) acc[i] = make_float4(0.f, 0.f, 0.f, 0.f);

    const float4* W4 = (const float4*)W;
    #pragma unroll 4
    for (int k = 0; k < HID; k += 4) {
        float4 w0 = W4[(k + 0) * 32 + cg];
        float4 w1 = W4[(k + 1) * 32 + cg];
        float4 w2 = W4[(k + 2) * 32 + cg];
        float4 w3 = W4[(k + 3) * 32 + cg];
        #pragma unroll
        for (int i = 0; i < 8; ++i) {
            float4 a = lds[rg * 8 + i][k >> 2];
            acc[i].x = fmaf(a.x, w0.x, acc[i].x); acc[i].y = fmaf(a.x, w0.y, acc[i].y);
            acc[i].z = fmaf(a.x, w0.z, acc[i].z); acc[i].w = fmaf(a.x, w0.w, acc[i].w);
            acc[i].x = fmaf(a.y, w1.x, acc[i].x); acc[i].y = fmaf(a.y, w1.y, acc[i].y);
            acc[i].z = fmaf(a.y, w1.z, acc[i].z); acc[i].w = fmaf(a.y, w1.w, acc[i].w);
            acc[i].x = fmaf(a.z, w2.x, acc[i].x); acc[i].y = fmaf(a.z, w2.y, acc[i].y);
            acc[i].z = fmaf(a.z, w2.z, acc[i].z); acc[i].w = fmaf(a.z, w2.w, acc[i].w);
            acc[i].x = fmaf(a.w, w3.x, acc[i].x); acc[i].y = fmaf(a.w, w3.y, acc[i].y);
            acc[i].z = fmaf(a.w, w3.z, acc[i].z); acc[i].w = fmaf(a.w, w3.w, acc[i].w);
        }
    }

    #pragma unroll
    for (int i = 0; i < 8; ++i) {
        int r = row0 + rg * 8 + i;
        if (r < n) ((float4*)T)[(size_t)r * 32 + cg] = acc[i];
    }
}

// ---------------- pull aggregation: O[i] = b + T[i]*dinv[i]^2 + sum_nbr T[s]*norm ----------------
// one wave (64 lanes) per node; lane = feature-pair (float2).
// Edge loop unrolled x8: 8 independent shfl-broadcasts -> 8 independent 512B
// gathers in flight -> 8 FMA pairs. Breaks the per-edge vmcnt(0) latency chain.
__global__ __launch_bounds__(256) void k_agg(const float* __restrict__ T,
                                             float* __restrict__ O,
                                             const int* __restrict__ rowptr,
                                             const int* __restrict__ csrc,
                                             const float* __restrict__ cnorm,
                                             const float* __restrict__ dinv,
                                             const float* __restrict__ bias, int n) {
    int wid = (blockIdx.x * 256 + threadIdx.x) >> 6;
    int lane = threadIdx.x & 63;
    if (wid >= n) return;
    const float2* T2 = (const float2*)T;
    float di = dinv[wid];
    float2 b2 = ((const float2*)bias)[lane];
    float2 self = T2[(size_t)wid * 64 + lane];
    float sn = di * di;
    float2 acc;
    acc.x = fmaf(self.x, sn, b2.x);
    acc.y = fmaf(self.y, sn, b2.y);
    int start = rowptr[wid];
    int deg = rowptr[wid + 1] - start;

    for (int j0 = 0; j0 < deg; j0 += 64) {
        int myj = j0 + lane;
        int s = 0; float w = 0.f;
        if (myj < deg) { s = csrc[start + myj]; w = cnorm[start + myj]; }
        int m = min(64, deg - j0);
        int jj = 0;
        for (; jj + 8 <= m; jj += 8) {
            int s0 = __shfl(s, jj + 0), s1 = __shfl(s, jj + 1);
            int s2 = __shfl(s, jj + 2), s3 = __shfl(s, jj + 3);
            int s4 = __shfl(s, jj + 4), s5 = __shfl(s, jj + 5);
            int s6 = __shfl(s, jj + 6), s7 = __shfl(s, jj + 7);
            float w0 = __shfl(w, jj + 0), w1 = __shfl(w, jj + 1);
            float w2 = __shfl(w, jj + 2), w3 = __shfl(w, jj + 3);
            float w4 = __shfl(w, jj + 4), w5 = __shfl(w, jj + 5);
            float w6 = __shfl(w, jj + 6), w7 = __shfl(w, jj + 7);
            float2 v0 = T2[(size_t)s0 * 64 + lane];
            float2 v1 = T2[(size_t)s1 * 64 + lane];
            float2 v2 = T2[(size_t)s2 * 64 + lane];
            float2 v3 = T2[(size_t)s3 * 64 + lane];
            float2 v4 = T2[(size_t)s4 * 64 + lane];
            float2 v5 = T2[(size_t)s5 * 64 + lane];
            float2 v6 = T2[(size_t)s6 * 64 + lane];
            float2 v7 = T2[(size_t)s7 * 64 + lane];
            acc.x = fmaf(w0, v0.x, acc.x); acc.y = fmaf(w0, v0.y, acc.y);
            acc.x = fmaf(w1, v1.x, acc.x); acc.y = fmaf(w1, v1.y, acc.y);
            acc.x = fmaf(w2, v2.x, acc.x); acc.y = fmaf(w2, v2.y, acc.y);
            acc.x = fmaf(w3, v3.x, acc.x); acc.y = fmaf(w3, v3.y, acc.y);
            acc.x = fmaf(w4, v4.x, acc.x); acc.y = fmaf(w4, v4.y, acc.y);
            acc.x = fmaf(w5, v5.x, acc.x); acc.y = fmaf(w5, v5.y, acc.y);
            acc.x = fmaf(w6, v6.x, acc.x); acc.y = fmaf(w6, v6.y, acc.y);
            acc.x = fmaf(w7, v7.x, acc.x); acc.y = fmaf(w7, v7.y, acc.y);
        }
        for (; jj < m; ++jj) {
            int sj = __shfl(s, jj);
            float wj = __shfl(w, jj);
            float2 v = T2[(size_t)sj * 64 + lane];
            acc.x = fmaf(wj, v.x, acc.x);
            acc.y = fmaf(wj, v.y, acc.y);
        }
    }
    ((float2*)O)[(size_t)wid * 64 + lane] = acc;
}

// ---------------- pooling: segment-sum over sorted batch ids ----------------
__global__ __launch_bounds__(256) void k_pool(const float* __restrict__ H,
                                              const int* __restrict__ batch,
                                              float* pooled, float* cnt, int n) {
    int gw = (blockIdx.x * 256 + threadIdx.x) >> 6;
    int lane = threadIdx.x & 63;
    int n0 = gw * 32;
    if (n0 >= n) return;
    int n1 = min(n0 + 32, n);
    const float2* H2 = (const float2*)H;
    int gprev = batch[n0];
    float2 acc = make_float2(0.f, 0.f);
    float runc = 0.f;
    for (int i = n0; i < n1; ++i) {
        int g = batch[i];
        if (g != gprev) {   // wave-uniform branch (batch same across lanes)
            atomicAdd(&pooled[gprev * HID + 2 * lane], acc.x);
            atomicAdd(&pooled[gprev * HID + 2 * lane + 1], acc.y);
            if (lane == 0) atomicAdd(&cnt[gprev], runc);
            acc = make_float2(0.f, 0.f); runc = 0.f; gprev = g;
        }
        float2 v = H2[(size_t)i * 64 + lane];
        acc.x += v.x; acc.y += v.y; runc += 1.f;
    }
    atomicAdd(&pooled[gprev * HID + 2 * lane], acc.x);
    atomicAdd(&pooled[gprev * HID + 2 * lane + 1], acc.y);
    if (lane == 0) atomicAdd(&cnt[gprev], runc);
}

// ---------------- head: out[g,c] = (pooled[g]/cnt[g]) @ Wc + bc ----------------
__global__ __launch_bounds__(256) void k_head(const float* __restrict__ pooled,
                                              const float* __restrict__ cnt,
                                              const float* __restrict__ Wc,
                                              const float* __restrict__ bc,
                                              float* __restrict__ out) {
    int idx = blockIdx.x * 256 + threadIdx.x;
    if (idx >= NGRAPH * NCLS) return;
    int g = idx >> 4, c = idx & 15;
    float inv = 1.0f / fmaxf(cnt[g], 1.0f);
    float s = 0.f;
    for (int k = 0; k < HID; ++k)
        s = fmaf(pooled[g * HID + k], Wc[k * NCLS + c], s);
    out[idx] = s * inv + bc[c];
}

extern "C" void kernel_launch(void* const* d_in, const int* in_sizes, int n_in,
                              void* d_out, int out_size, void* d_ws, size_t ws_size,
                              hipStream_t stream) {
    const float* x    = (const float*)d_in[0];
    const int*   ei   = (const int*)d_in[1];
    const int*   batch= (const int*)d_in[2];
    const float* W0   = (const float*)d_in[3];
    const float* b0   = (const float*)d_in[4];
    const float* W1   = (const float*)d_in[5];
    const float* b1   = (const float*)d_in[6];
    const float* W2   = (const float*)d_in[7];
    const float* b2   = (const float*)d_in[8];
    const float* Wc   = (const float*)d_in[9];
    const float* bc   = (const float*)d_in[10];
    float* out = (float*)d_out;

    const int N = in_sizes[0] / HID;       // 50000
    const int E = in_sizes[1] / 2;         // 800000
    const int* src = ei;
    const int* dst = ei + E;

    // workspace layout
    char* p = (char*)d_ws;
    auto alloc = [&](size_t bytes) { void* r = (void*)p; p += (bytes + 255) & ~(size_t)255; return r; };
    int*   counts = (int*)alloc((size_t)N * 4);
    int*   cursor = (int*)alloc((size_t)N * 4);
    float* dinv   = (float*)alloc((size_t)N * 4);
    int*   csum   = (int*)alloc(256 * 4);
    int*   coff   = (int*)alloc(256 * 4);
    int*   rowptr = (int*)alloc((size_t)(N + 1) * 4);
    int*   csrc   = (int*)alloc((size_t)E * 4);
    float* cnorm  = (float*)alloc((size_t)E * 4);
    float* pooled = (float*)alloc((size_t)NGRAPH * HID * 4);
    float* cnt    = (float*)alloc((size_t)NGRAPH * 4);
    float* bufA   = (float*)alloc((size_t)N * HID * 4);
    float* bufB   = (float*)alloc((size_t)N * HID * 4);

    const int NB = (N + CHUNK - 1) / CHUNK;

    k_init<<<(N + 255) / 256, 256, 0, stream>>>(counts, cursor, pooled, cnt, N);
    k_hist<<<(E + 255) / 256, 256, 0, stream>>>(dst, counts, E);
    k_dinv<<<(N + 255) / 256, 256, 0, stream>>>(counts, dinv, N);
    k_chunksum<<<NB, 256, 0, stream>>>(counts, csum, N);
    k_scanchunks<<<1, 64, 0, stream>>>(csum, coff, NB);
    k_rowptr<<<NB, 256, 0, stream>>>(counts, coff, rowptr, N, E);
    k_fill<<<(E + 255) / 256, 256, 0, stream>>>(src, dst, dinv, rowptr, cursor, csrc, cnorm, E);

    const int gemm_grid = (N + 63) / 64;
    const int agg_grid  = ((size_t)N * 64 + 255) / 256;

    // layer 0
    k_gemm<<<gemm_grid, 256, 0, stream>>>(x, W0, bufA, N, 0);
    k_agg<<<agg_grid, 256, 0, stream>>>(bufA, bufB, rowptr, csrc, cnorm, dinv, b0, N);
    // layer 1 (relu applied on GEMM input load)
    k_gemm<<<gemm_grid, 256, 0, stream>>>(bufB, W1, bufA, N, 1);
    k_agg<<<agg_grid, 256, 0, stream>>>(bufA, bufB, rowptr, csrc, cnorm, dinv, b1, N);
    // layer 2
    k_gemm<<<gemm_grid, 256, 0, stream>>>(bufB, W2, bufA, N, 1);
    k_agg<<<agg_grid, 256, 0, stream>>>(bufA, bufB, rowptr, csrc, cnorm, dinv, b2, N);

    // pooling + head
    const int pool_waves = (N + 31) / 32;
    k_pool<<<(pool_waves * 64 + 255) / 256, 256, 0, stream>>>(bufB, batch, pooled, cnt, N);
    k_head<<<(NGRAPH * NCLS + 255) / 256, 256, 0, stream>>>(pooled, cnt, Wc, bc, out);
}

// Round 4
// 316.890 us; speedup vs baseline: 2.1215x; 1.2534x over previous
//
#include <hip/hip_runtime.h>
#include <hip/hip_bf16.h>

#define HID 128
#define NCLS 16
#define NGRAPH 64
#define CHUNK 1024

// round-to-nearest-even f32 -> bf16 (deterministic, no NaN inputs here)
__device__ __forceinline__ unsigned int f2bf(float f) {
    unsigned int u = __float_as_uint(f);
    return (u + 0x7FFFu + ((u >> 16) & 1u)) >> 16;
}
__device__ __forceinline__ float bf2f_lo(unsigned int u) { return __uint_as_float(u << 16); }
__device__ __forceinline__ float bf2f_hi(unsigned int u) { return __uint_as_float(u & 0xFFFF0000u); }

// ---------------- init: zero accumulators ----------------
__global__ __launch_bounds__(256) void k_init(int* counts, int* cursor,
                                              float* pooled, float* cnt, int n) {
    int i = blockIdx.x * 256 + threadIdx.x;
    if (i < n) { counts[i] = 0; cursor[i] = 0; }
    if (i < NGRAPH * HID) pooled[i] = 0.0f;
    if (i < NGRAPH) cnt[i] = 0.0f;
}

// ---------------- degree histogram over dst ----------------
__global__ __launch_bounds__(256) void k_hist(const int* __restrict__ dst,
                                              int* counts, int e) {
    int i = blockIdx.x * 256 + threadIdx.x;
    if (i < e) atomicAdd(&counts[dst[i]], 1);
}

// ---------------- dinv = rsqrt(deg+1)  (self-loop) ----------------
__global__ __launch_bounds__(256) void k_dinv(const int* __restrict__ counts,
                                              float* dinv, int n) {
    int i = blockIdx.x * 256 + threadIdx.x;
    if (i < n) dinv[i] = rsqrtf((float)(counts[i] + 1));
}

// ---------------- scan step 1: per-chunk sums ----------------
__global__ __launch_bounds__(256) void k_chunksum(const int* __restrict__ counts,
                                                  int* csum, int n) {
    __shared__ int sdata[256];
    int b = blockIdx.x, t = threadIdx.x;
    int base = b * CHUNK + t * 4;
    int s = 0;
    #pragma unroll
    for (int j = 0; j < 4; ++j) { int i = base + j; if (i < n) s += counts[i]; }
    sdata[t] = s; __syncthreads();
    for (int off = 128; off > 0; off >>= 1) {
        if (t < off) sdata[t] += sdata[t + off];
        __syncthreads();
    }
    if (t == 0) csum[b] = sdata[0];
}

// ---------------- scan step 2: serial scan of chunk sums ----------------
__global__ void k_scanchunks(const int* __restrict__ csum, int* coff, int nb) {
    if (blockIdx.x == 0 && threadIdx.x == 0) {
        int run = 0;
        for (int b = 0; b < nb; ++b) { coff[b] = run; run += csum[b]; }
    }
}

// ---------------- scan step 3: per-chunk exclusive scan -> rowptr ----------------
__global__ __launch_bounds__(256) void k_rowptr(const int* __restrict__ counts,
                                                const int* __restrict__ coff,
                                                int* rowptr, int n, int e) {
    __shared__ int sincl[256];
    int b = blockIdx.x, t = threadIdx.x;
    int base = b * CHUNK + t * 4;
    int v[4]; int s = 0;
    #pragma unroll
    for (int j = 0; j < 4; ++j) { int i = base + j; v[j] = (i < n) ? counts[i] : 0; s += v[j]; }
    sincl[t] = s; __syncthreads();
    for (int off = 1; off < 256; off <<= 1) {
        int x = sincl[t];
        int y = (t >= off) ? sincl[t - off] : 0;
        __syncthreads();
        sincl[t] = x + y;
        __syncthreads();
    }
    int run = coff[b] + sincl[t] - s;
    #pragma unroll
    for (int j = 0; j < 4; ++j) {
        int i = base + j;
        if (i < n) { rowptr[i] = run; run += v[j]; }
    }
    if (b == 0 && t == 0) rowptr[n] = e;
}

// ---------------- CSR fill: interleaved (src, norm) 8B records ----------------
__global__ __launch_bounds__(256) void k_fill(const int* __restrict__ src,
                                              const int* __restrict__ dst,
                                              const float* __restrict__ dinv,
                                              const int* __restrict__ rowptr,
                                              int* cursor, uint2* epk, int e) {
    int i = blockIdx.x * 256 + threadIdx.x;
    if (i >= e) return;
    int s = src[i], d = dst[i];
    int pos = rowptr[d] + atomicAdd(&cursor[d], 1);
    epk[pos] = make_uint2((unsigned int)s, __float_as_uint(dinv[s] * dinv[d]));
}

// ---------------- GEMM: Tb[n,128](bf16) = (relu?)H[n,128] @ W[128,128] ----------------
// Register-tiled: 256 threads = 8 row-groups x 32 col-groups; thread: 8 rows x 4 cols.
__global__ __launch_bounds__(256) void k_gemm(const float* __restrict__ H,
                                              const float* __restrict__ W,
                                              unsigned int* __restrict__ Tb,  // packed 2xbf16
                                              int n, int relu_in) {
    __shared__ float4 lds[64][32];
    int t = threadIdx.x;
    int cg = t & 31;
    int rg = t >> 5;
    int row0 = blockIdx.x * 64;

    #pragma unroll
    for (int i = 0; i < 8; ++i) {
        int lr = rg + i * 8;
        int r = row0 + lr;
        float4 v = make_float4(0.f, 0.f, 0.f, 0.f);
        if (r < n) v = ((const float4*)H)[(size_t)r * 32 + cg];
        if (relu_in) {
            v.x = fmaxf(v.x, 0.f); v.y = fmaxf(v.y, 0.f);
            v.z = fmaxf(v.z, 0.f); v.w = fmaxf(v.w, 0.f);
        }
        lds[lr][cg] = v;
    }
    __syncthreads();

    float4 acc[8];
    #pragma unroll
    for (int i = 0; i < 8; ++i) acc[i] = make_float4(0.f, 0.f, 0.f, 0.f);

    const float4* W4 = (const float4*)W;
    #pragma unroll 4
    for (int k = 0; k < HID; k += 4) {
        float4 w0 = W4[(k + 0) * 32 + cg];
        float4 w1 = W4[(k + 1) * 32 + cg];
        float4 w2 = W4[(k + 2) * 32 + cg];
        float4 w3 = W4[(k + 3) * 32 + cg];
        #pragma unroll
        for (int i = 0; i < 8; ++i) {
            float4 a = lds[rg * 8 + i][k >> 2];
            acc[i].x = fmaf(a.x, w0.x, acc[i].x); acc[i].y = fmaf(a.x, w0.y, acc[i].y);
            acc[i].z = fmaf(a.x, w0.z, acc[i].z); acc[i].w = fmaf(a.x, w0.w, acc[i].w);
            acc[i].x = fmaf(a.y, w1.x, acc[i].x); acc[i].y = fmaf(a.y, w1.y, acc[i].y);
            acc[i].z = fmaf(a.y, w1.z, acc[i].z); acc[i].w = fmaf(a.y, w1.w, acc[i].w);
            acc[i].x = fmaf(a.z, w2.x, acc[i].x); acc[i].y = fmaf(a.z, w2.y, acc[i].y);
            acc[i].z = fmaf(a.z, w2.z, acc[i].z); acc[i].w = fmaf(a.z, w2.w, acc[i].w);
            acc[i].x = fmaf(a.w, w3.x, acc[i].x); acc[i].y = fmaf(a.w, w3.y, acc[i].y);
            acc[i].z = fmaf(a.w, w3.z, acc[i].z); acc[i].w = fmaf(a.w, w3.w, acc[i].w);
        }
    }

    #pragma unroll
    for (int i = 0; i < 8; ++i) {
        int r = row0 + rg * 8 + i;
        if (r < n) {
            unsigned int lo = f2bf(acc[i].x) | (f2bf(acc[i].y) << 16);
            unsigned int hi = f2bf(acc[i].z) | (f2bf(acc[i].w) << 16);
            ((uint2*)Tb)[(size_t)r * 32 + cg] = make_uint2(lo, hi);
        }
    }
}

// ---------------- pull aggregation (bf16 gather): ----------------
// O[i] = b + Tb[i]*dinv[i]^2 + sum_nbr Tb[s]*norm   (f32 accumulate)
// one wave per node; lane = feature-pair (one u32 = 2 bf16). Row = 256B.
__global__ __launch_bounds__(256) void k_agg(const unsigned int* __restrict__ Tb,
                                             float* __restrict__ O,
                                             const int* __restrict__ rowptr,
                                             const uint2* __restrict__ epk,
                                             const float* __restrict__ dinv,
                                             const float* __restrict__ bias, int n) {
    int wid = (blockIdx.x * 256 + threadIdx.x) >> 6;
    int lane = threadIdx.x & 63;
    if (wid >= n) return;
    float di = dinv[wid];
    float2 b2 = ((const float2*)bias)[lane];
    unsigned int us = Tb[(size_t)wid * 64 + lane];
    float sn = di * di;
    float2 acc;
    acc.x = fmaf(bf2f_lo(us), sn, b2.x);
    acc.y = fmaf(bf2f_hi(us), sn, b2.y);
    int start = rowptr[wid];
    int deg = rowptr[wid + 1] - start;

    for (int j0 = 0; j0 < deg; j0 += 64) {
        int myj = j0 + lane;
        unsigned int s = 0; float w = 0.f;
        if (myj < deg) {
            uint2 e = epk[start + myj];
            s = e.x; w = __uint_as_float(e.y);
        }
        int m = min(64, deg - j0);
        int jj = 0;
        for (; jj + 8 <= m; jj += 8) {
            int s0 = __shfl((int)s, jj + 0), s1 = __shfl((int)s, jj + 1);
            int s2 = __shfl((int)s, jj + 2), s3 = __shfl((int)s, jj + 3);
            int s4 = __shfl((int)s, jj + 4), s5 = __shfl((int)s, jj + 5);
            int s6 = __shfl((int)s, jj + 6), s7 = __shfl((int)s, jj + 7);
            float w0 = __shfl(w, jj + 0), w1 = __shfl(w, jj + 1);
            float w2 = __shfl(w, jj + 2), w3 = __shfl(w, jj + 3);
            float w4 = __shfl(w, jj + 4), w5 = __shfl(w, jj + 5);
            float w6 = __shfl(w, jj + 6), w7 = __shfl(w, jj + 7);
            unsigned int u0 = Tb[(size_t)s0 * 64 + lane];
            unsigned int u1 = Tb[(size_t)s1 * 64 + lane];
            unsigned int u2 = Tb[(size_t)s2 * 64 + lane];
            unsigned int u3 = Tb[(size_t)s3 * 64 + lane];
            unsigned int u4 = Tb[(size_t)s4 * 64 + lane];
            unsigned int u5 = Tb[(size_t)s5 * 64 + lane];
            unsigned int u6 = Tb[(size_t)s6 * 64 + lane];
            unsigned int u7 = Tb[(size_t)s7 * 64 + lane];
            acc.x = fmaf(w0, bf2f_lo(u0), acc.x); acc.y = fmaf(w0, bf2f_hi(u0), acc.y);
            acc.x = fmaf(w1, bf2f_lo(u1), acc.x); acc.y = fmaf(w1, bf2f_hi(u1), acc.y);
            acc.x = fmaf(w2, bf2f_lo(u2), acc.x); acc.y = fmaf(w2, bf2f_hi(u2), acc.y);
            acc.x = fmaf(w3, bf2f_lo(u3), acc.x); acc.y = fmaf(w3, bf2f_hi(u3), acc.y);
            acc.x = fmaf(w4, bf2f_lo(u4), acc.x); acc.y = fmaf(w4, bf2f_hi(u4), acc.y);
            acc.x = fmaf(w5, bf2f_lo(u5), acc.x); acc.y = fmaf(w5, bf2f_hi(u5), acc.y);
            acc.x = fmaf(w6, bf2f_lo(u6), acc.x); acc.y = fmaf(w6, bf2f_hi(u6), acc.y);
            acc.x = fmaf(w7, bf2f_lo(u7), acc.x); acc.y = fmaf(w7, bf2f_hi(u7), acc.y);
        }
        for (; jj < m; ++jj) {
            int sj = __shfl((int)s, jj);
            float wj = __shfl(w, jj);
            unsigned int u = Tb[(size_t)sj * 64 + lane];
            acc.x = fmaf(wj, bf2f_lo(u), acc.x);
            acc.y = fmaf(wj, bf2f_hi(u), acc.y);
        }
    }
    ((float2*)O)[(size_t)wid * 64 + lane] = acc;
}

// ---------------- pooling: segment-sum over sorted batch ids ----------------
__global__ __launch_bounds__(256) void k_pool(const float* __restrict__ H,
                                              const int* __restrict__ batch,
                                              float* pooled, float* cnt, int n) {
    int gw = (blockIdx.x * 256 + threadIdx.x) >> 6;
    int lane = threadIdx.x & 63;
    int n0 = gw * 32;
    if (n0 >= n) return;
    int n1 = min(n0 + 32, n);
    const float2* H2 = (const float2*)H;
    int gprev = batch[n0];
    float2 acc = make_float2(0.f, 0.f);
    float runc = 0.f;
    for (int i = n0; i < n1; ++i) {
        int g = batch[i];
        if (g != gprev) {
            atomicAdd(&pooled[gprev * HID + 2 * lane], acc.x);
            atomicAdd(&pooled[gprev * HID + 2 * lane + 1], acc.y);
            if (lane == 0) atomicAdd(&cnt[gprev], runc);
            acc = make_float2(0.f, 0.f); runc = 0.f; gprev = g;
        }
        float2 v = H2[(size_t)i * 64 + lane];
        acc.x += v.x; acc.y += v.y; runc += 1.f;
    }
    atomicAdd(&pooled[gprev * HID + 2 * lane], acc.x);
    atomicAdd(&pooled[gprev * HID + 2 * lane + 1], acc.y);
    if (lane == 0) atomicAdd(&cnt[gprev], runc);
}

// ---------------- head ----------------
__global__ __launch_bounds__(256) void k_head(const float* __restrict__ pooled,
                                              const float* __restrict__ cnt,
                                              const float* __restrict__ Wc,
                                              const float* __restrict__ bc,
                                              float* __restrict__ out) {
    int idx = blockIdx.x * 256 + threadIdx.x;
    if (idx >= NGRAPH * NCLS) return;
    int g = idx >> 4, c = idx & 15;
    float inv = 1.0f / fmaxf(cnt[g], 1.0f);
    float s = 0.f;
    for (int k = 0; k < HID; ++k)
        s = fmaf(pooled[g * HID + k], Wc[k * NCLS + c], s);
    out[idx] = s * inv + bc[c];
}

extern "C" void kernel_launch(void* const* d_in, const int* in_sizes, int n_in,
                              void* d_out, int out_size, void* d_ws, size_t ws_size,
                              hipStream_t stream) {
    const float* x    = (const float*)d_in[0];
    const int*   ei   = (const int*)d_in[1];
    const int*   batch= (const int*)d_in[2];
    const float* W0   = (const float*)d_in[3];
    const float* b0   = (const float*)d_in[4];
    const float* W1   = (const float*)d_in[5];
    const float* b1   = (const float*)d_in[6];
    const float* W2   = (const float*)d_in[7];
    const float* b2   = (const float*)d_in[8];
    const float* Wc   = (const float*)d_in[9];
    const float* bc   = (const float*)d_in[10];
    float* out = (float*)d_out;

    const int N = in_sizes[0] / HID;       // 50000
    const int E = in_sizes[1] / 2;         // 800000
    const int* src = ei;
    const int* dst = ei + E;

    char* p = (char*)d_ws;
    auto alloc = [&](size_t bytes) { void* r = (void*)p; p += (bytes + 255) & ~(size_t)255; return r; };
    int*   counts = (int*)alloc((size_t)N * 4);
    int*   cursor = (int*)alloc((size_t)N * 4);
    float* dinv   = (float*)alloc((size_t)N * 4);
    int*   csum   = (int*)alloc(256 * 4);
    int*   coff   = (int*)alloc(256 * 4);
    int*   rowptr = (int*)alloc((size_t)(N + 1) * 4);
    uint2* epk    = (uint2*)alloc((size_t)E * 8);
    float* pooled = (float*)alloc((size_t)NGRAPH * HID * 4);
    float* cnt    = (float*)alloc((size_t)NGRAPH * 4);
    unsigned int* Tb = (unsigned int*)alloc((size_t)N * HID * 2);  // bf16 packed
    float* bufF   = (float*)alloc((size_t)N * HID * 4);

    const int NB = (N + CHUNK - 1) / CHUNK;

    k_init<<<(N + 255) / 256, 256, 0, stream>>>(counts, cursor, pooled, cnt, N);
    k_hist<<<(E + 255) / 256, 256, 0, stream>>>(dst, counts, E);
    k_dinv<<<(N + 255) / 256, 256, 0, stream>>>(counts, dinv, N);
    k_chunksum<<<NB, 256, 0, stream>>>(counts, csum, N);
    k_scanchunks<<<1, 64, 0, stream>>>(csum, coff, NB);
    k_rowptr<<<NB, 256, 0, stream>>>(counts, coff, rowptr, N, E);
    k_fill<<<(E + 255) / 256, 256, 0, stream>>>(src, dst, dinv, rowptr, cursor, epk, E);

    const int gemm_grid = (N + 63) / 64;
    const int agg_grid  = ((size_t)N * 64 + 255) / 256;

    // layer 0
    k_gemm<<<gemm_grid, 256, 0, stream>>>(x, W0, Tb, N, 0);
    k_agg<<<agg_grid, 256, 0, stream>>>(Tb, bufF, rowptr, epk, dinv, b0, N);
    // layer 1 (relu applied on GEMM input load)
    k_gemm<<<gemm_grid, 256, 0, stream>>>(bufF, W1, Tb, N, 1);
    k_agg<<<agg_grid, 256, 0, stream>>>(Tb, bufF, rowptr, epk, dinv, b1, N);
    // layer 2
    k_gemm<<<gemm_grid, 256, 0, stream>>>(bufF, W2, Tb, N, 1);
    k_agg<<<agg_grid, 256, 0, stream>>>(Tb, bufF, rowptr, epk, dinv, b2, N);

    // pooling + head
    const int pool_waves = (N + 31) / 32;
    k_pool<<<(pool_waves * 64 + 255) / 256, 256, 0, stream>>>(bufF, batch, pooled, cnt, N);
    k_head<<<(NGRAPH * NCLS + 255) / 256, 256, 0, stream>>>(pooled, cnt, Wc, bc, out);
}

// Round 5
// 267.999 us; speedup vs baseline: 2.5086x; 1.1824x over previous
//
#include <hip/hip_runtime.h>
#include <hip/hip_bf16.h>
#include <hip/hip_fp16.h>

#define HID 128
#define NCLS 16
#define NGRAPH 64
#define CHUNK 1024

using bf16x8 = __attribute__((ext_vector_type(8))) short;
using f32x4  = __attribute__((ext_vector_type(4))) float;

// round-to-nearest-even f32 -> bf16
__device__ __forceinline__ unsigned int f2bf(float f) {
    unsigned int u = __float_as_uint(f);
    return (u + 0x7FFFu + ((u >> 16) & 1u)) >> 16;
}
__device__ __forceinline__ float bf2f_lo(unsigned int u) { return __uint_as_float(u << 16); }
__device__ __forceinline__ float bf2f_hi(unsigned int u) { return __uint_as_float(u & 0xFFFF0000u); }

// ---------------- init: zero accumulators ----------------
__global__ __launch_bounds__(256) void k_init(int* counts, float* pooled, float* cnt, int n) {
    int i = blockIdx.x * 256 + threadIdx.x;
    if (i < n) counts[i] = 0;
    if (i < NGRAPH * HID) pooled[i] = 0.0f;
    if (i < NGRAPH) cnt[i] = 0.0f;
}

// ---------------- degree histogram over dst + per-edge rank ----------------
__global__ __launch_bounds__(256) void k_hist(const int* __restrict__ dst,
                                              int* counts, int* rank, int e) {
    int i = blockIdx.x * 256 + threadIdx.x;
    if (i < e) rank[i] = atomicAdd(&counts[dst[i]], 1);
}

// ---------------- dinv = rsqrt(deg+1)  (self-loop) ----------------
__global__ __launch_bounds__(256) void k_dinv(const int* __restrict__ counts,
                                              float* dinv, int n) {
    int i = blockIdx.x * 256 + threadIdx.x;
    if (i < n) dinv[i] = rsqrtf((float)(counts[i] + 1));
}

// ---------------- scan step 1: per-chunk sums ----------------
__global__ __launch_bounds__(256) void k_chunksum(const int* __restrict__ counts,
                                                  int* csum, int n) {
    __shared__ int sdata[256];
    int b = blockIdx.x, t = threadIdx.x;
    int base = b * CHUNK + t * 4;
    int s = 0;
    #pragma unroll
    for (int j = 0; j < 4; ++j) { int i = base + j; if (i < n) s += counts[i]; }
    sdata[t] = s; __syncthreads();
    for (int off = 128; off > 0; off >>= 1) {
        if (t < off) sdata[t] += sdata[t + off];
        __syncthreads();
    }
    if (t == 0) csum[b] = sdata[0];
}

// ---------------- scan step 2: serial scan of chunk sums ----------------
__global__ void k_scanchunks(const int* __restrict__ csum, int* coff, int nb) {
    if (blockIdx.x == 0 && threadIdx.x == 0) {
        int run = 0;
        for (int b = 0; b < nb; ++b) { coff[b] = run; run += csum[b]; }
    }
}

// ---------------- scan step 3: per-chunk exclusive scan -> rowptr ----------------
__global__ __launch_bounds__(256) void k_rowptr(const int* __restrict__ counts,
                                                const int* __restrict__ coff,
                                                int* rowptr, int n, int e) {
    __shared__ int sincl[256];
    int b = blockIdx.x, t = threadIdx.x;
    int base = b * CHUNK + t * 4;
    int v[4]; int s = 0;
    #pragma unroll
    for (int j = 0; j < 4; ++j) { int i = base + j; v[j] = (i < n) ? counts[i] : 0; s += v[j]; }
    sincl[t] = s; __syncthreads();
    for (int off = 1; off < 256; off <<= 1) {
        int x = sincl[t];
        int y = (t >= off) ? sincl[t - off] : 0;
        __syncthreads();
        sincl[t] = x + y;
        __syncthreads();
    }
    int run = coff[b] + sincl[t] - s;
    #pragma unroll
    for (int j = 0; j < 4; ++j) {
        int i = base + j;
        if (i < n) { rowptr[i] = run; run += v[j]; }
    }
    if (b == 0 && t == 0) rowptr[n] = e;
}

// ---------------- CSR fill: 4B records {u16 src | fp16 norm}, no atomics ----------------
__global__ __launch_bounds__(256) void k_fill(const int* __restrict__ src,
                                              const int* __restrict__ dst,
                                              const int* __restrict__ rank,
                                              const float* __restrict__ dinv,
                                              const int* __restrict__ rowptr,
                                              unsigned int* __restrict__ epk, int e) {
    int i = blockIdx.x * 256 + threadIdx.x;
    if (i >= e) return;
    int s = src[i], d = dst[i];
    int pos = rowptr[d] + rank[i];
    __half h = __float2half(dinv[s] * dinv[d]);
    unsigned int hu = (unsigned int)__half_as_ushort(h);
    epk[pos] = (unsigned int)s | (hu << 16);
}

// ---------------- W prep: Wt[m][col*128+k] = bf16(W[m][k*128+col]) ----------------
__global__ __launch_bounds__(256) void k_wprep(const float* __restrict__ W0,
                                               const float* __restrict__ W1,
                                               const float* __restrict__ W2,
                                               unsigned short* __restrict__ Wt) {
    int tid = blockIdx.x * 256 + threadIdx.x;
    if (tid >= 3 * HID * HID) return;
    int m = tid >> 14;           // /16384
    int r = tid & 16383;
    int c = r >> 7, k = r & 127;
    const float* W = (m == 0) ? W0 : (m == 1) ? W1 : W2;
    Wt[tid] = (unsigned short)f2bf(W[k * HID + c]);
}

// ---------------- MFMA GEMM: Tb[n,128](bf16) = bf16((relu?)H) @ bf16(W) ----------------
// 256 threads = 4 waves; block tile 64 rows x 128 cols; wave w: rows w*16..+15.
// A staged in LDS bf16 with ((row&7)<<4) XOR swizzle (kills the 16-way
// ds_read_b128 conflict of 256B-stride rows). B frags direct from Wt (L1-hot).
__global__ __launch_bounds__(256) void k_gemm(const float* __restrict__ H,
                                              const unsigned short* __restrict__ Wt,
                                              unsigned short* __restrict__ Tb16,
                                              int n, int relu_in) {
    __shared__ char ldsA[64 * 256];   // 64 rows x 128 bf16 (256B/row), swizzled
    int t = threadIdx.x;
    int cg = t & 31;          // float4 col group (4 features)
    int rg = t >> 5;          // 0..7
    int row0 = blockIdx.x * 64;

    #pragma unroll
    for (int i = 0; i < 8; ++i) {
        int lr = rg + i * 8;
        int r = row0 + lr;
        float4 v = make_float4(0.f, 0.f, 0.f, 0.f);
        if (r < n) v = ((const float4*)H)[(size_t)r * 32 + cg];
        if (relu_in) {
            v.x = fmaxf(v.x, 0.f); v.y = fmaxf(v.y, 0.f);
            v.z = fmaxf(v.z, 0.f); v.w = fmaxf(v.w, 0.f);
        }
        uint2 pk;
        pk.x = f2bf(v.x) | (f2bf(v.y) << 16);
        pk.y = f2bf(v.z) | (f2bf(v.w) << 16);
        int byte = lr * 256 + cg * 8;
        *(uint2*)(ldsA + (byte ^ ((lr & 7) << 4))) = pk;
    }
    __syncthreads();

    int lane = t & 63;
    int w = t >> 6;                       // wave 0..3
    int rsub = lane & 15;                 // A row within wave tile / B col within ntile
    int kg = lane >> 4;                   // k-group 0..3
    int rowIdx = w * 16 + rsub;
    int abase = rowIdx * 256 + kg * 16;   // + kk*64 per k-step
    int aswz = (rowIdx & 7) << 4;

    f32x4 acc[8];
    #pragma unroll
    for (int nt = 0; nt < 8; ++nt) acc[nt] = (f32x4)(0.f);

    #pragma unroll
    for (int kk = 0; kk < 4; ++kk) {
        bf16x8 a = *(const bf16x8*)(ldsA + ((abase + kk * 64) ^ aswz));
        int k0 = kk * 32 + kg * 8;
        #pragma unroll
        for (int nt = 0; nt < 8; ++nt) {
            int col = nt * 16 + rsub;
            bf16x8 b = *(const bf16x8*)(Wt + col * 128 + k0);
            acc[nt] = __builtin_amdgcn_mfma_f32_16x16x32_bf16(a, b, acc[nt], 0, 0, 0);
        }
    }

    // C/D layout: col = lane&15, row = (lane>>4)*4 + reg   [verified m89]
    #pragma unroll
    for (int nt = 0; nt < 8; ++nt) {
        #pragma unroll
        for (int j = 0; j < 4; ++j) {
            int row = row0 + w * 16 + kg * 4 + j;
            int col = nt * 16 + rsub;
            if (row < n) Tb16[(size_t)row * 128 + col] = (unsigned short)f2bf(acc[nt][j]);
        }
    }
}

// ---------------- pull aggregation (bf16 gather, f32 accumulate) ----------------
// one wave per node; lane = feature-pair (u32 = 2 bf16). Row = 256B.
__global__ __launch_bounds__(256) void k_agg(const unsigned int* __restrict__ Tb,
                                             float* __restrict__ O,
                                             const int* __restrict__ rowptr,
                                             const unsigned int* __restrict__ epk,
                                             const float* __restrict__ dinv,
                                             const float* __restrict__ bias, int n) {
    int wid = (blockIdx.x * 256 + threadIdx.x) >> 6;
    int lane = threadIdx.x & 63;
    if (wid >= n) return;
    float di = dinv[wid];
    float2 b2 = ((const float2*)bias)[lane];
    unsigned int us = Tb[(size_t)wid * 64 + lane];
    float sn = di * di;
    float2 acc;
    acc.x = fmaf(bf2f_lo(us), sn, b2.x);
    acc.y = fmaf(bf2f_hi(us), sn, b2.y);
    int start = rowptr[wid];
    int deg = rowptr[wid + 1] - start;

    for (int j0 = 0; j0 < deg; j0 += 64) {
        int myj = j0 + lane;
        unsigned int rec = 0;
        if (myj < deg) rec = epk[start + myj];
        int m = min(64, deg - j0);
        int jj = 0;
        for (; jj + 8 <= m; jj += 8) {
            int r0 = __shfl((int)rec, jj + 0), r1 = __shfl((int)rec, jj + 1);
            int r2 = __shfl((int)rec, jj + 2), r3 = __shfl((int)rec, jj + 3);
            int r4 = __shfl((int)rec, jj + 4), r5 = __shfl((int)rec, jj + 5);
            int r6 = __shfl((int)rec, jj + 6), r7 = __shfl((int)rec, jj + 7);
            unsigned int u0 = Tb[(size_t)(r0 & 0xFFFF) * 64 + lane];
            unsigned int u1 = Tb[(size_t)(r1 & 0xFFFF) * 64 + lane];
            unsigned int u2 = Tb[(size_t)(r2 & 0xFFFF) * 64 + lane];
            unsigned int u3 = Tb[(size_t)(r3 & 0xFFFF) * 64 + lane];
            unsigned int u4 = Tb[(size_t)(r4 & 0xFFFF) * 64 + lane];
            unsigned int u5 = Tb[(size_t)(r5 & 0xFFFF) * 64 + lane];
            unsigned int u6 = Tb[(size_t)(r6 & 0xFFFF) * 64 + lane];
            unsigned int u7 = Tb[(size_t)(r7 & 0xFFFF) * 64 + lane];
            float w0 = __half2float(__ushort_as_half((unsigned short)((unsigned)r0 >> 16)));
            float w1 = __half2float(__ushort_as_half((unsigned short)((unsigned)r1 >> 16)));
            float w2 = __half2float(__ushort_as_half((unsigned short)((unsigned)r2 >> 16)));
            float w3 = __half2float(__ushort_as_half((unsigned short)((unsigned)r3 >> 16)));
            float w4 = __half2float(__ushort_as_half((unsigned short)((unsigned)r4 >> 16)));
            float w5 = __half2float(__ushort_as_half((unsigned short)((unsigned)r5 >> 16)));
            float w6 = __half2float(__ushort_as_half((unsigned short)((unsigned)r6 >> 16)));
            float w7 = __half2float(__ushort_as_half((unsigned short)((unsigned)r7 >> 16)));
            acc.x = fmaf(w0, bf2f_lo(u0), acc.x); acc.y = fmaf(w0, bf2f_hi(u0), acc.y);
            acc.x = fmaf(w1, bf2f_lo(u1), acc.x); acc.y = fmaf(w1, bf2f_hi(u1), acc.y);
            acc.x = fmaf(w2, bf2f_lo(u2), acc.x); acc.y = fmaf(w2, bf2f_hi(u2), acc.y);
            acc.x = fmaf(w3, bf2f_lo(u3), acc.x); acc.y = fmaf(w3, bf2f_hi(u3), acc.y);
            acc.x = fmaf(w4, bf2f_lo(u4), acc.x); acc.y = fmaf(w4, bf2f_hi(u4), acc.y);
            acc.x = fmaf(w5, bf2f_lo(u5), acc.x); acc.y = fmaf(w5, bf2f_hi(u5), acc.y);
            acc.x = fmaf(w6, bf2f_lo(u6), acc.x); acc.y = fmaf(w6, bf2f_hi(u6), acc.y);
            acc.x = fmaf(w7, bf2f_lo(u7), acc.x); acc.y = fmaf(w7, bf2f_hi(u7), acc.y);
        }
        for (; jj < m; ++jj) {
            int rj = __shfl((int)rec, jj);
            unsigned int u = Tb[(size_t)(rj & 0xFFFF) * 64 + lane];
            float wj = __half2float(__ushort_as_half((unsigned short)((unsigned)rj >> 16)));
            acc.x = fmaf(wj, bf2f_lo(u), acc.x);
            acc.y = fmaf(wj, bf2f_hi(u), acc.y);
        }
    }
    ((float2*)O)[(size_t)wid * 64 + lane] = acc;
}

// ---------------- pooling: segment-sum over sorted batch ids ----------------
__global__ __launch_bounds__(256) void k_pool(const float* __restrict__ H,
                                              const int* __restrict__ batch,
                                              float* pooled, float* cnt, int n) {
    int gw = (blockIdx.x * 256 + threadIdx.x) >> 6;
    int lane = threadIdx.x & 63;
    int n0 = gw * 32;
    if (n0 >= n) return;
    int n1 = min(n0 + 32, n);
    const float2* H2 = (const float2*)H;
    int gprev = batch[n0];
    float2 acc = make_float2(0.f, 0.f);
    float runc = 0.f;
    for (int i = n0; i < n1; ++i) {
        int g = batch[i];
        if (g != gprev) {
            atomicAdd(&pooled[gprev * HID + 2 * lane], acc.x);
            atomicAdd(&pooled[gprev * HID + 2 * lane + 1], acc.y);
            if (lane == 0) atomicAdd(&cnt[gprev], runc);
            acc = make_float2(0.f, 0.f); runc = 0.f; gprev = g;
        }
        float2 v = H2[(size_t)i * 64 + lane];
        acc.x += v.x; acc.y += v.y; runc += 1.f;
    }
    atomicAdd(&pooled[gprev * HID + 2 * lane], acc.x);
    atomicAdd(&pooled[gprev * HID + 2 * lane + 1], acc.y);
    if (lane == 0) atomicAdd(&cnt[gprev], runc);
}

// ---------------- head ----------------
__global__ __launch_bounds__(256) void k_head(const float* __restrict__ pooled,
                                              const float* __restrict__ cnt,
                                              const float* __restrict__ Wc,
                                              const float* __restrict__ bc,
                                              float* __restrict__ out) {
    int idx = blockIdx.x * 256 + threadIdx.x;
    if (idx >= NGRAPH * NCLS) return;
    int g = idx >> 4, c = idx & 15;
    float inv = 1.0f / fmaxf(cnt[g], 1.0f);
    float s = 0.f;
    for (int k = 0; k < HID; ++k)
        s = fmaf(pooled[g * HID + k], Wc[k * NCLS + c], s);
    out[idx] = s * inv + bc[c];
}

extern "C" void kernel_launch(void* const* d_in, const int* in_sizes, int n_in,
                              void* d_out, int out_size, void* d_ws, size_t ws_size,
                              hipStream_t stream) {
    const float* x    = (const float*)d_in[0];
    const int*   ei   = (const int*)d_in[1];
    const int*   batch= (const int*)d_in[2];
    const float* W0   = (const float*)d_in[3];
    const float* b0   = (const float*)d_in[4];
    const float* W1   = (const float*)d_in[5];
    const float* b1   = (const float*)d_in[6];
    const float* W2   = (const float*)d_in[7];
    const float* b2   = (const float*)d_in[8];
    const float* Wc   = (const float*)d_in[9];
    const float* bc   = (const float*)d_in[10];
    float* out = (float*)d_out;

    const int N = in_sizes[0] / HID;       // 50000
    const int E = in_sizes[1] / 2;         // 800000
    const int* src = ei;
    const int* dst = ei + E;

    char* p = (char*)d_ws;
    auto alloc = [&](size_t bytes) { void* r = (void*)p; p += (bytes + 255) & ~(size_t)255; return r; };
    int*   counts = (int*)alloc((size_t)N * 4);
    float* dinv   = (float*)alloc((size_t)N * 4);
    int*   rank   = (int*)alloc((size_t)E * 4);
    int*   csum   = (int*)alloc(256 * 4);
    int*   coff   = (int*)alloc(256 * 4);
    int*   rowptr = (int*)alloc((size_t)(N + 1) * 4);
    unsigned int* epk = (unsigned int*)alloc((size_t)E * 4);
    float* pooled = (float*)alloc((size_t)NGRAPH * HID * 4);
    float* cnt    = (float*)alloc((size_t)NGRAPH * 4);
    unsigned short* Tb16 = (unsigned short*)alloc((size_t)N * HID * 2);
    float* bufF   = (float*)alloc((size_t)N * HID * 4);
    unsigned short* Wt = (unsigned short*)alloc((size_t)3 * HID * HID * 2);

    const int NB = (N + CHUNK - 1) / CHUNK;

    k_init<<<(N + 255) / 256, 256, 0, stream>>>(counts, pooled, cnt, N);
    k_hist<<<(E + 255) / 256, 256, 0, stream>>>(dst, counts, rank, E);
    k_dinv<<<(N + 255) / 256, 256, 0, stream>>>(counts, dinv, N);
    k_chunksum<<<NB, 256, 0, stream>>>(counts, csum, N);
    k_scanchunks<<<1, 64, 0, stream>>>(csum, coff, NB);
    k_rowptr<<<NB, 256, 0, stream>>>(counts, coff, rowptr, N, E);
    k_fill<<<(E + 255) / 256, 256, 0, stream>>>(src, dst, rank, dinv, rowptr, epk, E);
    k_wprep<<<(3 * HID * HID + 255) / 256, 256, 0, stream>>>(W0, W1, W2, Wt);

    const int gemm_grid = (N + 63) / 64;
    const int agg_grid  = ((size_t)N * 64 + 255) / 256;

    // layer 0
    k_gemm<<<gemm_grid, 256, 0, stream>>>(x, Wt, Tb16, N, 0);
    k_agg<<<agg_grid, 256, 0, stream>>>((const unsigned int*)Tb16, bufF, rowptr, epk, dinv, b0, N);
    // layer 1 (relu applied on GEMM input load)
    k_gemm<<<gemm_grid, 256, 0, stream>>>(bufF, Wt + 16384, Tb16, N, 1);
    k_agg<<<agg_grid, 256, 0, stream>>>((const unsigned int*)Tb16, bufF, rowptr, epk, dinv, b1, N);
    // layer 2
    k_gemm<<<gemm_grid, 256, 0, stream>>>(bufF, Wt + 32768, Tb16, N, 1);
    k_agg<<<agg_grid, 256, 0, stream>>>((const unsigned int*)Tb16, bufF, rowptr, epk, dinv, b2, N);

    // pooling + head
    const int pool_waves = (N + 31) / 32;
    k_pool<<<(pool_waves * 64 + 255) / 256, 256, 0, stream>>>(bufF, batch, pooled, cnt, N);
    k_head<<<(NGRAPH * NCLS + 255) / 256, 256, 0, stream>>>(pooled, cnt, Wc, bc, out);
}

// Round 6
// 264.478 us; speedup vs baseline: 2.5420x; 1.0133x over previous
//
#include <hip/hip_runtime.h>
#include <hip/hip_bf16.h>
#include <hip/hip_fp16.h>

#define HID 128
#define NCLS 16
#define NGRAPH 64
#define CHUNK 1024

using bf16x8 = __attribute__((ext_vector_type(8))) short;
using f32x4  = __attribute__((ext_vector_type(4))) float;

// round-to-nearest-even f32 -> bf16
__device__ __forceinline__ unsigned int f2bf(float f) {
    unsigned int u = __float_as_uint(f);
    return (u + 0x7FFFu + ((u >> 16) & 1u)) >> 16;
}
__device__ __forceinline__ float bf2f_lo(unsigned int u) { return __uint_as_float(u << 16); }
__device__ __forceinline__ float bf2f_hi(unsigned int u) { return __uint_as_float(u & 0xFFFF0000u); }

// ---------------- init: zero accumulators ----------------
__global__ __launch_bounds__(256) void k_init(int* counts, float* pooled, float* cnt, int n) {
    int i = blockIdx.x * 256 + threadIdx.x;
    if (i < n) counts[i] = 0;
    if (i < NGRAPH * HID) pooled[i] = 0.0f;
    if (i < NGRAPH) cnt[i] = 0.0f;
}

// ---------------- degree histogram over dst + per-edge rank ----------------
__global__ __launch_bounds__(256) void k_hist(const int* __restrict__ dst,
                                              int* counts, int* rank, int e) {
    int i = blockIdx.x * 256 + threadIdx.x;
    if (i < e) rank[i] = atomicAdd(&counts[dst[i]], 1);
}

// ---------------- dinv = rsqrt(deg+1)  (self-loop) ----------------
__global__ __launch_bounds__(256) void k_dinv(const int* __restrict__ counts,
                                              float* dinv, int n) {
    int i = blockIdx.x * 256 + threadIdx.x;
    if (i < n) dinv[i] = rsqrtf((float)(counts[i] + 1));
}

// ---------------- scan step 1: per-chunk sums ----------------
__global__ __launch_bounds__(256) void k_chunksum(const int* __restrict__ counts,
                                                  int* csum, int n) {
    __shared__ int sdata[256];
    int b = blockIdx.x, t = threadIdx.x;
    int base = b * CHUNK + t * 4;
    int s = 0;
    #pragma unroll
    for (int j = 0; j < 4; ++j) { int i = base + j; if (i < n) s += counts[i]; }
    sdata[t] = s; __syncthreads();
    for (int off = 128; off > 0; off >>= 1) {
        if (t < off) sdata[t] += sdata[t + off];
        __syncthreads();
    }
    if (t == 0) csum[b] = sdata[0];
}

// ---------------- scan step 2: serial scan of chunk sums ----------------
__global__ void k_scanchunks(const int* __restrict__ csum, int* coff, int nb) {
    if (blockIdx.x == 0 && threadIdx.x == 0) {
        int run = 0;
        for (int b = 0; b < nb; ++b) { coff[b] = run; run += csum[b]; }
    }
}

// ---------------- scan step 3: per-chunk exclusive scan -> rowptr ----------------
__global__ __launch_bounds__(256) void k_rowptr(const int* __restrict__ counts,
                                                const int* __restrict__ coff,
                                                int* rowptr, int n, int e) {
    __shared__ int sincl[256];
    int b = blockIdx.x, t = threadIdx.x;
    int base = b * CHUNK + t * 4;
    int v[4]; int s = 0;
    #pragma unroll
    for (int j = 0; j < 4; ++j) { int i = base + j; v[j] = (i < n) ? counts[i] : 0; s += v[j]; }
    sincl[t] = s; __syncthreads();
    for (int off = 1; off < 256; off <<= 1) {
        int x = sincl[t];
        int y = (t >= off) ? sincl[t - off] : 0;
        __syncthreads();
        sincl[t] = x + y;
        __syncthreads();
    }
    int run = coff[b] + sincl[t] - s;
    #pragma unroll
    for (int j = 0; j < 4; ++j) {
        int i = base + j;
        if (i < n) { rowptr[i] = run; run += v[j]; }
    }
    if (b == 0 && t == 0) rowptr[n] = e;
}

// ---------------- CSR fill: 4B records {u16 src | fp16 norm}, no atomics ----------------
__global__ __launch_bounds__(256) void k_fill(const int* __restrict__ src,
                                              const int* __restrict__ dst,
                                              const int* __restrict__ rank,
                                              const float* __restrict__ dinv,
                                              const int* __restrict__ rowptr,
                                              unsigned int* __restrict__ epk, int e) {
    int i = blockIdx.x * 256 + threadIdx.x;
    if (i >= e) return;
    int s = src[i], d = dst[i];
    int pos = rowptr[d] + rank[i];
    __half h = __float2half(dinv[s] * dinv[d]);
    unsigned int hu = (unsigned int)__half_as_ushort(h);
    epk[pos] = (unsigned int)s | (hu << 16);
}

// ---------------- W prep: Wt[m][col*128+k] = bf16(W[m][k*128+col]) ----------------
__global__ __launch_bounds__(256) void k_wprep(const float* __restrict__ W0,
                                               const float* __restrict__ W1,
                                               const float* __restrict__ W2,
                                               unsigned short* __restrict__ Wt) {
    int tid = blockIdx.x * 256 + threadIdx.x;
    if (tid >= 3 * HID * HID) return;
    int m = tid >> 14;           // /16384
    int r = tid & 16383;
    int c = r >> 7, k = r & 127;
    const float* W = (m == 0) ? W0 : (m == 1) ? W1 : W2;
    Wt[tid] = (unsigned short)f2bf(W[k * HID + c]);
}

// ---------------- MFMA GEMM (f32 input, layer 0) ----------------
// 256 threads = 4 waves; block tile 64 rows x 128 cols.
// A staged in LDS bf16, ((row&7)<<4) XOR swizzle. B direct from Wt (L1-hot).
__global__ __launch_bounds__(256) void k_gemm_f32(const float* __restrict__ H,
                                                  const unsigned short* __restrict__ Wt,
                                                  unsigned short* __restrict__ Tb16, int n) {
    __shared__ char ldsA[64 * 256];
    int t = threadIdx.x;
    int cg = t & 31;
    int rg = t >> 5;
    int row0 = blockIdx.x * 64;

    #pragma unroll
    for (int i = 0; i < 8; ++i) {
        int lr = rg + i * 8;
        int r = row0 + lr;
        float4 v = make_float4(0.f, 0.f, 0.f, 0.f);
        if (r < n) v = ((const float4*)H)[(size_t)r * 32 + cg];
        uint2 pk;
        pk.x = f2bf(v.x) | (f2bf(v.y) << 16);
        pk.y = f2bf(v.z) | (f2bf(v.w) << 16);
        int byte = lr * 256 + cg * 8;
        *(uint2*)(ldsA + (byte ^ ((lr & 7) << 4))) = pk;
    }
    __syncthreads();

    int lane = t & 63;
    int w = t >> 6;
    int rsub = lane & 15;
    int kg = lane >> 4;
    int rowIdx = w * 16 + rsub;
    int abase = rowIdx * 256 + kg * 16;
    int aswz = (rowIdx & 7) << 4;

    f32x4 acc[8];
    #pragma unroll
    for (int nt = 0; nt < 8; ++nt) acc[nt] = (f32x4)(0.f);

    #pragma unroll
    for (int kk = 0; kk < 4; ++kk) {
        bf16x8 a = *(const bf16x8*)(ldsA + ((abase + kk * 64) ^ aswz));
        int k0 = kk * 32 + kg * 8;
        #pragma unroll
        for (int nt = 0; nt < 8; ++nt) {
            int col = nt * 16 + rsub;
            bf16x8 b = *(const bf16x8*)(Wt + col * 128 + k0);
            acc[nt] = __builtin_amdgcn_mfma_f32_16x16x32_bf16(a, b, acc[nt], 0, 0, 0);
        }
    }

    // C/D layout: col = lane&15, row = (lane>>4)*4 + reg
    #pragma unroll
    for (int nt = 0; nt < 8; ++nt) {
        #pragma unroll
        for (int j = 0; j < 4; ++j) {
            int row = row0 + w * 16 + kg * 4 + j;
            int col = nt * 16 + rsub;
            if (row < n) Tb16[(size_t)row * 128 + col] = (unsigned short)f2bf(acc[nt][j]);
        }
    }
}

// ---------------- MFMA GEMM (bf16 input, layers 1/2; relu already fused in agg) ----------------
__global__ __launch_bounds__(256) void k_gemm_bf16(const unsigned short* __restrict__ Hb,
                                                   const unsigned short* __restrict__ Wt,
                                                   unsigned short* __restrict__ Tb16, int n) {
    __shared__ char ldsA[64 * 256];
    int t = threadIdx.x;
    int row0 = blockIdx.x * 64;
    int c16 = t & 15;             // 16B chunk within row
    int rbase = t >> 4;           // 0..15

    #pragma unroll
    for (int i = 0; i < 4; ++i) {
        int lr = rbase + i * 16;
        int r = row0 + lr;
        uint4 v = make_uint4(0u, 0u, 0u, 0u);
        if (r < n) v = *(const uint4*)(Hb + (size_t)r * 128 + c16 * 8);
        int byte = lr * 256 + c16 * 16;
        *(uint4*)(ldsA + (byte ^ ((lr & 7) << 4))) = v;
    }
    __syncthreads();

    int lane = t & 63;
    int w = t >> 6;
    int rsub = lane & 15;
    int kg = lane >> 4;
    int rowIdx = w * 16 + rsub;
    int abase = rowIdx * 256 + kg * 16;
    int aswz = (rowIdx & 7) << 4;

    f32x4 acc[8];
    #pragma unroll
    for (int nt = 0; nt < 8; ++nt) acc[nt] = (f32x4)(0.f);

    #pragma unroll
    for (int kk = 0; kk < 4; ++kk) {
        bf16x8 a = *(const bf16x8*)(ldsA + ((abase + kk * 64) ^ aswz));
        int k0 = kk * 32 + kg * 8;
        #pragma unroll
        for (int nt = 0; nt < 8; ++nt) {
            int col = nt * 16 + rsub;
            bf16x8 b = *(const bf16x8*)(Wt + col * 128 + k0);
            acc[nt] = __builtin_amdgcn_mfma_f32_16x16x32_bf16(a, b, acc[nt], 0, 0, 0);
        }
    }

    #pragma unroll
    for (int nt = 0; nt < 8; ++nt) {
        #pragma unroll
        for (int j = 0; j < 4; ++j) {
            int row = row0 + w * 16 + kg * 4 + j;
            int col = nt * 16 + rsub;
            if (row < n) Tb16[(size_t)row * 128 + col] = (unsigned short)f2bf(acc[nt][j]);
        }
    }
}

// ---------------- pull aggregation (bf16 gather, f32 accumulate) ----------------
// one wave per node; lane = feature-pair (u32 = 2 bf16). Row = 256B.
// Gather unrolled x16 (16 loads in flight). mode 0: write relu'd bf16 (layers
// 0/1 -> next GEMM; error-neutral, GEMM rounded to bf16 anyway). mode 1: f32.
__global__ __launch_bounds__(256) void k_agg(const unsigned int* __restrict__ Tb,
                                             unsigned int* __restrict__ outB,
                                             float* __restrict__ outF,
                                             const int* __restrict__ rowptr,
                                             const unsigned int* __restrict__ epk,
                                             const float* __restrict__ dinv,
                                             const float* __restrict__ bias,
                                             int n, int mode) {
    int wid = (blockIdx.x * 256 + threadIdx.x) >> 6;
    int lane = threadIdx.x & 63;
    if (wid >= n) return;
    float di = dinv[wid];
    float2 b2 = ((const float2*)bias)[lane];
    unsigned int us = Tb[(size_t)wid * 64 + lane];
    float sn = di * di;
    float2 acc;
    acc.x = fmaf(bf2f_lo(us), sn, b2.x);
    acc.y = fmaf(bf2f_hi(us), sn, b2.y);
    int start = rowptr[wid];
    int deg = rowptr[wid + 1] - start;

    for (int j0 = 0; j0 < deg; j0 += 64) {
        int myj = j0 + lane;
        unsigned int rec = 0;
        if (myj < deg) rec = epk[start + myj];
        int m = min(64, deg - j0);
        int jj = 0;
        for (; jj + 16 <= m; jj += 16) {
            unsigned int rr[16], uu[16];
            #pragma unroll
            for (int k = 0; k < 16; ++k) rr[k] = (unsigned int)__shfl((int)rec, jj + k);
            #pragma unroll
            for (int k = 0; k < 16; ++k) uu[k] = Tb[(size_t)(rr[k] & 0xFFFFu) * 64 + lane];
            #pragma unroll
            for (int k = 0; k < 16; ++k) {
                float wk = __half2float(__ushort_as_half((unsigned short)(rr[k] >> 16)));
                acc.x = fmaf(wk, bf2f_lo(uu[k]), acc.x);
                acc.y = fmaf(wk, bf2f_hi(uu[k]), acc.y);
            }
        }
        for (; jj + 4 <= m; jj += 4) {
            unsigned int rr[4], uu[4];
            #pragma unroll
            for (int k = 0; k < 4; ++k) rr[k] = (unsigned int)__shfl((int)rec, jj + k);
            #pragma unroll
            for (int k = 0; k < 4; ++k) uu[k] = Tb[(size_t)(rr[k] & 0xFFFFu) * 64 + lane];
            #pragma unroll
            for (int k = 0; k < 4; ++k) {
                float wk = __half2float(__ushort_as_half((unsigned short)(rr[k] >> 16)));
                acc.x = fmaf(wk, bf2f_lo(uu[k]), acc.x);
                acc.y = fmaf(wk, bf2f_hi(uu[k]), acc.y);
            }
        }
        for (; jj < m; ++jj) {
            unsigned int rj = (unsigned int)__shfl((int)rec, jj);
            unsigned int u = Tb[(size_t)(rj & 0xFFFFu) * 64 + lane];
            float wj = __half2float(__ushort_as_half((unsigned short)(rj >> 16)));
            acc.x = fmaf(wj, bf2f_lo(u), acc.x);
            acc.y = fmaf(wj, bf2f_hi(u), acc.y);
        }
    }

    if (mode == 0) {
        float rx = fmaxf(acc.x, 0.f), ry = fmaxf(acc.y, 0.f);
        outB[(size_t)wid * 64 + lane] = f2bf(rx) | (f2bf(ry) << 16);
    } else {
        ((float2*)outF)[(size_t)wid * 64 + lane] = acc;
    }
}

// ---------------- pooling: segment-sum over sorted batch ids ----------------
__global__ __launch_bounds__(256) void k_pool(const float* __restrict__ H,
                                              const int* __restrict__ batch,
                                              float* pooled, float* cnt, int n) {
    int gw = (blockIdx.x * 256 + threadIdx.x) >> 6;
    int lane = threadIdx.x & 63;
    int n0 = gw * 32;
    if (n0 >= n) return;
    int n1 = min(n0 + 32, n);
    const float2* H2 = (const float2*)H;
    int gprev = batch[n0];
    float2 acc = make_float2(0.f, 0.f);
    float runc = 0.f;
    for (int i = n0; i < n1; ++i) {
        int g = batch[i];
        if (g != gprev) {
            atomicAdd(&pooled[gprev * HID + 2 * lane], acc.x);
            atomicAdd(&pooled[gprev * HID + 2 * lane + 1], acc.y);
            if (lane == 0) atomicAdd(&cnt[gprev], runc);
            acc = make_float2(0.f, 0.f); runc = 0.f; gprev = g;
        }
        float2 v = H2[(size_t)i * 64 + lane];
        acc.x += v.x; acc.y += v.y; runc += 1.f;
    }
    atomicAdd(&pooled[gprev * HID + 2 * lane], acc.x);
    atomicAdd(&pooled[gprev * HID + 2 * lane + 1], acc.y);
    if (lane == 0) atomicAdd(&cnt[gprev], runc);
}

// ---------------- head ----------------
__global__ __launch_bounds__(256) void k_head(const float* __restrict__ pooled,
                                              const float* __restrict__ cnt,
                                              const float* __restrict__ Wc,
                                              const float* __restrict__ bc,
                                              float* __restrict__ out) {
    int idx = blockIdx.x * 256 + threadIdx.x;
    if (idx >= NGRAPH * NCLS) return;
    int g = idx >> 4, c = idx & 15;
    float inv = 1.0f / fmaxf(cnt[g], 1.0f);
    float s = 0.f;
    for (int k = 0; k < HID; ++k)
        s = fmaf(pooled[g * HID + k], Wc[k * NCLS + c], s);
    out[idx] = s * inv + bc[c];
}

extern "C" void kernel_launch(void* const* d_in, const int* in_sizes, int n_in,
                              void* d_out, int out_size, void* d_ws, size_t ws_size,
                              hipStream_t stream) {
    const float* x    = (const float*)d_in[0];
    const int*   ei   = (const int*)d_in[1];
    const int*   batch= (const int*)d_in[2];
    const float* W0   = (const float*)d_in[3];
    const float* b0   = (const float*)d_in[4];
    const float* W1   = (const float*)d_in[5];
    const float* b1   = (const float*)d_in[6];
    const float* W2   = (const float*)d_in[7];
    const float* b2   = (const float*)d_in[8];
    const float* Wc   = (const float*)d_in[9];
    const float* bc   = (const float*)d_in[10];
    float* out = (float*)d_out;

    const int N = in_sizes[0] / HID;       // 50000
    const int E = in_sizes[1] / 2;         // 800000
    const int* src = ei;
    const int* dst = ei + E;

    char* p = (char*)d_ws;
    auto alloc = [&](size_t bytes) { void* r = (void*)p; p += (bytes + 255) & ~(size_t)255; return r; };
    int*   counts = (int*)alloc((size_t)N * 4);
    float* dinv   = (float*)alloc((size_t)N * 4);
    int*   rank   = (int*)alloc((size_t)E * 4);
    int*   csum   = (int*)alloc(256 * 4);
    int*   coff   = (int*)alloc(256 * 4);
    int*   rowptr = (int*)alloc((size_t)(N + 1) * 4);
    unsigned int* epk = (unsigned int*)alloc((size_t)E * 4);
    float* pooled = (float*)alloc((size_t)NGRAPH * HID * 4);
    float* cnt    = (float*)alloc((size_t)NGRAPH * 4);
    unsigned short* Tb16 = (unsigned short*)alloc((size_t)N * HID * 2);
    unsigned short* Hb16 = (unsigned short*)alloc((size_t)N * HID * 2);
    float* bufF   = (float*)alloc((size_t)N * HID * 4);
    unsigned short* Wt = (unsigned short*)alloc((size_t)3 * HID * HID * 2);

    const int NB = (N + CHUNK - 1) / CHUNK;

    k_init<<<(N + 255) / 256, 256, 0, stream>>>(counts, pooled, cnt, N);
    k_hist<<<(E + 255) / 256, 256, 0, stream>>>(dst, counts, rank, E);
    k_dinv<<<(N + 255) / 256, 256, 0, stream>>>(counts, dinv, N);
    k_chunksum<<<NB, 256, 0, stream>>>(counts, csum, N);
    k_scanchunks<<<1, 64, 0, stream>>>(csum, coff, NB);
    k_rowptr<<<NB, 256, 0, stream>>>(counts, coff, rowptr, N, E);
    k_fill<<<(E + 255) / 256, 256, 0, stream>>>(src, dst, rank, dinv, rowptr, epk, E);
    k_wprep<<<(3 * HID * HID + 255) / 256, 256, 0, stream>>>(W0, W1, W2, Wt);

    const int gemm_grid = (N + 63) / 64;
    const int agg_grid  = ((size_t)N * 64 + 255) / 256;

    // layer 0
    k_gemm_f32<<<gemm_grid, 256, 0, stream>>>(x, Wt, Tb16, N);
    k_agg<<<agg_grid, 256, 0, stream>>>((const unsigned int*)Tb16, (unsigned int*)Hb16, nullptr,
                                        rowptr, epk, dinv, b0, N, 0);
    // layer 1
    k_gemm_bf16<<<gemm_grid, 256, 0, stream>>>(Hb16, Wt + 16384, Tb16, N);
    k_agg<<<agg_grid, 256, 0, stream>>>((const unsigned int*)Tb16, (unsigned int*)Hb16, nullptr,
                                        rowptr, epk, dinv, b1, N, 0);
    // layer 2
    k_gemm_bf16<<<gemm_grid, 256, 0, stream>>>(Hb16, Wt + 32768, Tb16, N);
    k_agg<<<agg_grid, 256, 0, stream>>>((const unsigned int*)Tb16, nullptr, bufF,
                                        rowptr, epk, dinv, b2, N, 1);

    // pooling + head
    const int pool_waves = (N + 31) / 32;
    k_pool<<<(pool_waves * 64 + 255) / 256, 256, 0, stream>>>(bufF, batch, pooled, cnt, N);
    k_head<<<(NGRAPH * NCLS + 255) / 256, 256, 0, stream>>>(pooled, cnt, Wc, bc, out);
}